// Round 4
// baseline (378.113 us; speedup 1.0000x reference)
//
#include <hip/hip_runtime.h>

// ---------------------------------------------------------------------------
// ImprovedLinkingPredictor round 4.
// - pair_mlp: 256-thread blocks, 64-j tiles -> ~34 KB LDS -> 4 blocks/CU
//   (4-way block overlap to hide barriers/latency; was 2-way).
// - B[j] adds via transposed bf16 Bt[o][j]: 16x dwordx2 instead of 64x dword.
// - pack_all c1/c2 vectorized (float4) to kill the serial tail.
// ---------------------------------------------------------------------------

typedef __attribute__((ext_vector_type(8))) __bf16 bf16x8;   // MFMA A/B frag
typedef __attribute__((ext_vector_type(4))) float f32x4;     // MFMA C/D frag

__device__ __forceinline__ float bf2f(unsigned short u) {
    return __uint_as_float(((unsigned int)u) << 16);
}
__device__ __forceinline__ unsigned short f2bf(float f) {
    union { __bf16 b; unsigned short u; } cv;
    cv.b = (__bf16)f;            // v_cvt bf16 on gfx950, RNE
    return cv.u;
}

// ---------------- pack: bf16 casts + fragment-major weight layouts ----------
__global__ __launch_bounds__(256) void pack_all(
    const float* __restrict__ features, const float* __restrict__ in_proj_w,
    const float* __restrict__ out_proj_w, const float* __restrict__ w1,
    const float* __restrict__ w2, const float* __restrict__ w3,
    const float* __restrict__ w4, const float* __restrict__ b1,
    const float* __restrict__ ln_g, const float* __restrict__ ln_b,
    const float* __restrict__ b2,
    unsigned short* __restrict__ featb, unsigned short* __restrict__ inWb,
    unsigned short* __restrict__ outWb, unsigned short* __restrict__ wABb,
    unsigned short* __restrict__ w1c_f, unsigned short* __restrict__ w2g_f,
    unsigned short* __restrict__ w3_f, unsigned short* __restrict__ w4_f,
    float* __restrict__ biasAB, float* __restrict__ w1s_p,
    float* __restrict__ c1, float* __restrict__ c2)
{
    int t = blockIdx.x * 256 + threadIdx.x;
    if (t < 196608) {
        featb[t] = f2bf(features[t]);
    } else if (t < 393216) {
        int u = t - 196608; inWb[u] = f2bf(in_proj_w[u]);
    } else if (t < 458752) {
        int u = t - 393216; outWb[u] = f2bf(out_proj_w[u]);
    } else if (t < 589824) {                  // wABb = [w1a ; w1b] rows
        int u = t - 458752; int n = u >> 8, k = u & 255;
        float v = (n < 256) ? w1[n * 771 + k] : w1[(n - 256) * 771 + 256 + k];
        wABb[u] = f2bf(v);
    } else if (t < 655360) {                  // w1c_f (frag-major, K=256,N=256)
        int u = t - 589824;
        int e = u & 7, lane = (u >> 3) & 63, f = u >> 9;
        int l15 = lane & 15, quad = lane >> 4;
        int ct = f & 15, kc = f >> 4;
        int o = ct * 16 + l15, k = kc * 32 + quad * 8 + e;
        w1c_f[u] = f2bf(w1[o * 771 + 512 + k]);
    } else if (t < 688128) {                  // w2g_f = (w2 * ln_g) frag-major
        int u = t - 655360;
        int e = u & 7, lane = (u >> 3) & 63, f = u >> 9;
        int l15 = lane & 15, quad = lane >> 4;
        int ct = f & 7, kc = f >> 3;
        int o = ct * 16 + l15, k = kc * 32 + quad * 8 + e;
        w2g_f[u] = f2bf(w2[o * 256 + k] * ln_g[k]);
    } else if (t < 696320) {                  // w3_f (K=128,N=64)
        int u = t - 688128;
        int e = u & 7, lane = (u >> 3) & 63, f = u >> 9;
        int l15 = lane & 15, quad = lane >> 4;
        int ct = f & 3, kc = f >> 2;
        int o = ct * 16 + l15, k = kc * 32 + quad * 8 + e;
        w3_f[u] = f2bf(w3[o * 128 + k]);
    } else if (t < 698368) {                  // w4_f (K=64,N=32)
        int u = t - 696320;
        int e = u & 7, lane = (u >> 3) & 63, f = u >> 9;
        int l15 = lane & 15, quad = lane >> 4;
        int ct = f & 1, kc = f >> 1;
        int o = ct * 16 + l15, k = kc * 32 + quad * 8 + e;
        w4_f[u] = f2bf(w4[o * 64 + k]);
    } else if (t < 698880) {                  // biasAB
        int u = t - 698368;
        biasAB[u] = (u < 256) ? b1[u] : 0.0f;
    } else if (t < 699648) {                  // w1s_p[s*256+o]
        int u = t - 698880;
        int s = u >> 8, o = u & 255;
        w1s_p[u] = w1[o * 771 + 768 + s];
    } else if (t < 699776) {                  // c1/c2 (LN folding constants)
        int p = t - 699648;
        float s2 = 0.f, s1 = 0.f;
        for (int k = 0; k < 256; k += 4) {
            float4 w = *reinterpret_cast<const float4*>(&w2[p * 256 + k]);
            float4 g = *reinterpret_cast<const float4*>(&ln_g[k]);
            float4 lb = *reinterpret_cast<const float4*>(&ln_b[k]);
            s2 += g.x * w.x + g.y * w.y + g.z * w.z + g.w * w.w;
            s1 += lb.x * w.x + lb.y * w.y + lb.z * w.z + lb.w * w.w;
        }
        c2[p] = s2;
        c1[p] = s1 + b2[p];
    }
}

// ---------------- bf16 MFMA GEMM: C[M,N] = A[M,K] @ W[N,K]^T + bias --------
// Columns >= tcol0 (if Vt) are written transposed bf16 into Vt (row stride 768).
__global__ __launch_bounds__(256) void gemm_bf(
    const unsigned short* __restrict__ A, const unsigned short* __restrict__ W,
    const float* __restrict__ bias, float* __restrict__ Cf,
    unsigned short* __restrict__ Cbf, unsigned short* __restrict__ Vt,
    int N, int K, int ldc, int tcol0)
{
    const int wv = threadIdx.x >> 6, lane = threadIdx.x & 63;
    const int l15 = lane & 15, quad = lane >> 4;
    const int row0 = blockIdx.x * 64 + wv * 16;
    const int col0 = blockIdx.y * 64;
    f32x4 acc[4] = {};
    for (int kc = 0; kc < (K >> 5); ++kc) {
        bf16x8 a = *reinterpret_cast<const bf16x8*>(&A[(row0 + l15) * K + kc * 32 + quad * 8]);
#pragma unroll
        for (int ct = 0; ct < 4; ++ct) {
            bf16x8 b = *reinterpret_cast<const bf16x8*>(&W[(col0 + ct * 16 + l15) * K + kc * 32 + quad * 8]);
            acc[ct] = __builtin_amdgcn_mfma_f32_16x16x32_bf16(a, b, acc[ct], 0, 0, 0);
        }
    }
#pragma unroll
    for (int ct = 0; ct < 4; ++ct)
#pragma unroll
        for (int r = 0; r < 4; ++r) {
            int row = row0 + quad * 4 + r, col = col0 + ct * 16 + l15;
            float v = acc[ct][r] + bias[col];
            if (Vt && col >= tcol0) {
                Vt[(col - tcol0) * 768 + row] = f2bf(v);
            } else {
                if (Cf)  Cf[row * ldc + col] = v;
                if (Cbf) Cbf[row * ldc + col] = f2bf(v);
            }
        }
}

// ---------------- fused MFMA attention -------------------------------------
#define SP 776   // 768 + 8 shorts pad

__global__ __launch_bounds__(256) void attn_mfma(
    const unsigned short* __restrict__ qkvb, const unsigned short* __restrict__ Vt,
    unsigned short* __restrict__ Obf)
{
    __shared__ __align__(16) unsigned short smS[64 * SP];
    const int h = blockIdx.x, q0 = blockIdx.y * 64, hb = h * 32;
    const int tid = threadIdx.x, wave = tid >> 6, lane = tid & 63;
    const int l15 = lane & 15, quad = lane >> 4;

    bf16x8 af[4];
#pragma unroll
    for (int mt = 0; mt < 4; ++mt)
        af[mt] = *reinterpret_cast<const bf16x8*>(&qkvb[(q0 + mt * 16 + l15) * 768 + hb + quad * 8]);
#pragma unroll
    for (int ct = 0; ct < 12; ++ct) {
        int n0 = wave * 192 + ct * 16;
        bf16x8 b = *reinterpret_cast<const bf16x8*>(&qkvb[(n0 + l15) * 768 + 256 + hb + quad * 8]);
#pragma unroll
        for (int mt = 0; mt < 4; ++mt) {
            f32x4 c = {};
            c = __builtin_amdgcn_mfma_f32_16x16x32_bf16(af[mt], b, c, 0, 0, 0);
#pragma unroll
            for (int r = 0; r < 4; ++r)
                smS[(mt * 16 + quad * 4 + r) * SP + n0 + l15] =
                    f2bf(c[r] * 0.17677669529663689f);
        }
    }
    __syncthreads();

    {   // row softmax: 4 threads per row, 192 cols each
        const int row = tid >> 2, part = tid & 3;
        unsigned short* rp = &smS[row * SP + part * 192];
        float mx = -3.0e38f;
#pragma unroll
        for (int c8 = 0; c8 < 24; ++c8) {
            uint4 v = *reinterpret_cast<const uint4*>(&rp[c8 * 8]);
            const unsigned short* pe = reinterpret_cast<const unsigned short*>(&v);
#pragma unroll
            for (int e = 0; e < 8; ++e) mx = fmaxf(mx, bf2f(pe[e]));
        }
        mx = fmaxf(mx, __shfl_xor(mx, 1, 64));
        mx = fmaxf(mx, __shfl_xor(mx, 2, 64));
        float ls = 0.f;
#pragma unroll
        for (int c8 = 0; c8 < 24; ++c8) {
            uint4 v = *reinterpret_cast<const uint4*>(&rp[c8 * 8]);
            const unsigned short* pe = reinterpret_cast<const unsigned short*>(&v);
            unsigned short o8[8];
#pragma unroll
            for (int e = 0; e < 8; ++e) {
                float ev = __expf(bf2f(pe[e]) - mx);
                ls += ev;
                o8[e] = f2bf(ev);
            }
            *reinterpret_cast<uint4*>(&rp[c8 * 8]) = *reinterpret_cast<const uint4*>(o8);
        }
        ls += __shfl_xor(ls, 1, 64);
        ls += __shfl_xor(ls, 2, 64);
        float inv = 1.0f / ls;
#pragma unroll
        for (int c8 = 0; c8 < 24; ++c8) {
            uint4 v = *reinterpret_cast<const uint4*>(&rp[c8 * 8]);
            const unsigned short* pe = reinterpret_cast<const unsigned short*>(&v);
            unsigned short o8[8];
#pragma unroll
            for (int e = 0; e < 8; ++e) o8[e] = f2bf(bf2f(pe[e]) * inv);
            *reinterpret_cast<uint4*>(&rp[c8 * 8]) = *reinterpret_cast<const uint4*>(o8);
        }
    }
    // PV consumes only this wave's own rows -> no barrier needed.
    f32x4 accp[2] = {};
    for (int kc = 0; kc < 24; ++kc) {
        bf16x8 a = *reinterpret_cast<const bf16x8*>(&smS[(wave * 16 + l15) * SP + kc * 32 + quad * 8]);
#pragma unroll
        for (int ct = 0; ct < 2; ++ct) {
            bf16x8 b = *reinterpret_cast<const bf16x8*>(&Vt[(hb + ct * 16 + l15) * 768 + kc * 32 + quad * 8]);
            accp[ct] = __builtin_amdgcn_mfma_f32_16x16x32_bf16(a, b, accp[ct], 0, 0, 0);
        }
    }
#pragma unroll
    for (int ct = 0; ct < 2; ++ct)
#pragma unroll
        for (int r = 0; r < 4; ++r) {
            int row = q0 + wave * 16 + quad * 4 + r;
            Obf[row * 256 + hb + ct * 16 + l15] = f2bf(accp[ct][r]);
        }
}

// ---------------- fused pair MLP: 1 i x 64 j, 256 thr, 4 blocks/CU ---------
#define S1 264
#define S2 136
#define S3 72

__global__ __launch_bounds__(256, 4) void pair_mlp(
    const float* __restrict__ att, const unsigned short* __restrict__ attb,
    const float* __restrict__ Aonly, const unsigned short* __restrict__ Btb,
    const unsigned short* __restrict__ w1c_f, const unsigned short* __restrict__ w2g_f,
    const unsigned short* __restrict__ w3_f, const unsigned short* __restrict__ w4_f,
    const float* __restrict__ w1s_p, const float* __restrict__ boxes,
    const float* __restrict__ c1, const float* __restrict__ c2,
    const float* __restrict__ b3, const float* __restrict__ b4,
    const float* __restrict__ w5, const float* __restrict__ b5,
    float* __restrict__ out)
{
    __shared__ __align__(16) unsigned short smA[64 * S1];    // 33.8 KB
    __shared__ float s_xd[64], s_ayd[64], s_yd[64];
    __shared__ float s_rsum[64][2], s_rssq[64][2];
    __shared__ float s_l5[64][2];

    const int i    = blockIdx.x;
    const int j0   = blockIdx.y * 64;
    const int tid  = threadIdx.x;
    const int wave = tid >> 6;
    const int lane = tid & 63;
    const int l15  = lane & 15;
    const int quad = lane >> 4;
    const int wr   = wave >> 1;            // 0..1 : 32-row group
    const int wc   = wave & 1;             // 0..1 : 128-col half
    const int arow0 = wr * 32;

    if (tid < 64) {
        int j = j0 + tid;
        float xd = fabsf(boxes[i * 4 + 0] - boxes[j * 4 + 0]);
        float yd = boxes[i * 4 + 1] - boxes[j * 4 + 1];
        s_xd[tid] = xd; s_yd[tid] = yd; s_ayd[tid] = fabsf(yd);
    }
    // scaled A-tile: smA[j_local][d] = bf16(att_j[d] * att_i[d])
#pragma unroll
    for (int it = 0; it < 8; ++it) {
        int c = tid + it * 256;
        int r = c >> 5, cc = (c & 31) << 3;
        uint4 v = *reinterpret_cast<const uint4*>(&attb[(j0 + r) * 256 + cc]);
        const unsigned short* pj = reinterpret_cast<const unsigned short*>(&v);
        float4 A0 = *reinterpret_cast<const float4*>(&att[i * 256 + cc]);
        float4 A1 = *reinterpret_cast<const float4*>(&att[i * 256 + cc + 4]);
        float ai[8] = {A0.x, A0.y, A0.z, A0.w, A1.x, A1.y, A1.z, A1.w};
        unsigned short o8[8];
#pragma unroll
        for (int e = 0; e < 8; ++e) o8[e] = f2bf(bf2f(pj[e]) * ai[e]);
        *reinterpret_cast<uint4*>(&smA[r * S1 + cc]) = *reinterpret_cast<const uint4*>(o8);
    }
    __syncthreads();                                          // B0

    // ======== GEMM1 (barrier-free): cross = scaledA @ w1c^T ========
    f32x4 acc[2][8] = {};
    for (int kc = 0; kc < 8; ++kc) {
        bf16x8 a0 = *reinterpret_cast<const bf16x8*>(&smA[(arow0      + l15) * S1 + kc * 32 + quad * 8]);
        bf16x8 a1 = *reinterpret_cast<const bf16x8*>(&smA[(arow0 + 16 + l15) * S1 + kc * 32 + quad * 8]);
#pragma unroll
        for (int ct = 0; ct < 8; ++ct) {
            bf16x8 b = *reinterpret_cast<const bf16x8*>(&w1c_f[((kc * 16 + wc * 8 + ct) * 64 + lane) * 8]);
            acc[0][ct] = __builtin_amdgcn_mfma_f32_16x16x32_bf16(a0, b, acc[0][ct], 0, 0, 0);
            acc[1][ct] = __builtin_amdgcn_mfma_f32_16x16x32_bf16(a1, b, acc[1][ct], 0, 0, 0);
        }
    }

    // ---- epilogue1: + A[i] + Bt[j] + spatial, relu, stats ----
    float vsum[2][4] = {}, vssq[2][4] = {};
#pragma unroll
    for (int ct = 0; ct < 8; ++ct) {
        int o = wc * 128 + ct * 16 + l15;
        float Ai = Aonly[i * 256 + o];
        float w0 = w1s_p[o], wv1 = w1s_p[256 + o], wv2 = w1s_p[512 + o];
#pragma unroll
        for (int rt = 0; rt < 2; ++rt) {
            uint2 bv = *reinterpret_cast<const uint2*>(&Btb[o * 768 + j0 + arow0 + rt * 16 + quad * 4]);
            const unsigned short* bs = reinterpret_cast<const unsigned short*>(&bv);
#pragma unroll
            for (int r = 0; r < 4; ++r) {
                int m = arow0 + rt * 16 + quad * 4 + r;
                float v = acc[rt][ct][r] + Ai + bf2f(bs[r])
                        + s_xd[m] * w0 + s_ayd[m] * wv1 + s_yd[m] * wv2;
                v = fmaxf(v, 0.f);
                acc[rt][ct][r] = v;
                vsum[rt][r] += v; vssq[rt][r] += v * v;
            }
        }
    }
#pragma unroll
    for (int mask = 1; mask < 16; mask <<= 1)
#pragma unroll
        for (int rt = 0; rt < 2; ++rt)
#pragma unroll
            for (int r = 0; r < 4; ++r) {
                vsum[rt][r] += __shfl_xor(vsum[rt][r], mask, 64);
                vssq[rt][r] += __shfl_xor(vssq[rt][r], mask, 64);
            }
    if (l15 == 0)
#pragma unroll
        for (int rt = 0; rt < 2; ++rt)
#pragma unroll
            for (int r = 0; r < 4; ++r) {
                int m = arow0 + rt * 16 + quad * 4 + r;
                s_rsum[m][wc] = vsum[rt][r];
                s_rssq[m][wc] = vssq[rt][r];
            }
    __syncthreads();                                          // B1 scaledA done
    // ---- write raw relu'd h1 (bf16); LN folded into GEMM2 ----
#pragma unroll
    for (int ct = 0; ct < 8; ++ct) {
        int o = wc * 128 + ct * 16 + l15;
#pragma unroll
        for (int rt = 0; rt < 2; ++rt)
#pragma unroll
            for (int r = 0; r < 4; ++r) {
                int m = arow0 + rt * 16 + quad * 4 + r;
                smA[m * S1 + o] = f2bf(acc[rt][ct][r]);
            }
    }
    __syncthreads();                                          // B2

    // ======== GEMM2 (barrier-free): S = h1 @ w2g^T ========
    f32x4 acc2[2][4] = {};
    for (int kc = 0; kc < 8; ++kc) {
        bf16x8 a0 = *reinterpret_cast<const bf16x8*>(&smA[(arow0      + l15) * S1 + kc * 32 + quad * 8]);
        bf16x8 a1 = *reinterpret_cast<const bf16x8*>(&smA[(arow0 + 16 + l15) * S1 + kc * 32 + quad * 8]);
#pragma unroll
        for (int ct = 0; ct < 4; ++ct) {
            bf16x8 b = *reinterpret_cast<const bf16x8*>(&w2g_f[((kc * 8 + wc * 4 + ct) * 64 + lane) * 8]);
            acc2[0][ct] = __builtin_amdgcn_mfma_f32_16x16x32_bf16(a0, b, acc2[0][ct], 0, 0, 0);
            acc2[1][ct] = __builtin_amdgcn_mfma_f32_16x16x32_bf16(a1, b, acc2[1][ct], 0, 0, 0);
        }
    }
    float mu[2][4], rs[2][4];
#pragma unroll
    for (int rt = 0; rt < 2; ++rt)
#pragma unroll
        for (int r = 0; r < 4; ++r) {
            int m = arow0 + rt * 16 + quad * 4 + r;
            float sm = (s_rsum[m][0] + s_rsum[m][1]) * (1.0f / 256.0f);
            float sq = (s_rssq[m][0] + s_rssq[m][1]) * (1.0f / 256.0f);
            mu[rt][r] = sm;
            rs[rt][r] = rsqrtf(sq - sm * sm + 1e-5f);
        }
    __syncthreads();                                          // B3 h1 reads done
#pragma unroll
    for (int ct = 0; ct < 4; ++ct) {
        int p = wc * 64 + ct * 16 + l15;
        float C1 = c1[p], C2 = c2[p];
#pragma unroll
        for (int rt = 0; rt < 2; ++rt)
#pragma unroll
            for (int r = 0; r < 4; ++r) {
                int m = arow0 + rt * 16 + quad * 4 + r;
                float v = rs[rt][r] * (acc2[rt][ct][r] - mu[rt][r] * C2) + C1;
                smA[m * S2 + p] = f2bf(fmaxf(v, 0.f));
            }
    }
    __syncthreads();                                          // B4

    // ======== GEMM3: h3 = h2 @ w3^T, relu ========
    f32x4 acc3[2][2] = {};
    for (int kc = 0; kc < 4; ++kc) {
        bf16x8 a0 = *reinterpret_cast<const bf16x8*>(&smA[(arow0      + l15) * S2 + kc * 32 + quad * 8]);
        bf16x8 a1 = *reinterpret_cast<const bf16x8*>(&smA[(arow0 + 16 + l15) * S2 + kc * 32 + quad * 8]);
#pragma unroll
        for (int ct = 0; ct < 2; ++ct) {
            bf16x8 b = *reinterpret_cast<const bf16x8*>(&w3_f[((kc * 4 + wc * 2 + ct) * 64 + lane) * 8]);
            acc3[0][ct] = __builtin_amdgcn_mfma_f32_16x16x32_bf16(a0, b, acc3[0][ct], 0, 0, 0);
            acc3[1][ct] = __builtin_amdgcn_mfma_f32_16x16x32_bf16(a1, b, acc3[1][ct], 0, 0, 0);
        }
    }
    __syncthreads();                                          // B5
#pragma unroll
    for (int rt = 0; rt < 2; ++rt)
#pragma unroll
        for (int ct = 0; ct < 2; ++ct) {
            int o = wc * 32 + ct * 16 + l15;
            float bb = b3[o];
#pragma unroll
            for (int r = 0; r < 4; ++r) {
                int m = arow0 + rt * 16 + quad * 4 + r;
                smA[m * S3 + o] = f2bf(fmaxf(acc3[rt][ct][r] + bb, 0.f));
            }
        }
    __syncthreads();                                          // B6

    // ======== GEMM4 + head ========
    f32x4 acc4[2] = {};
#pragma unroll
    for (int kc = 0; kc < 2; ++kc) {
        bf16x8 a0 = *reinterpret_cast<const bf16x8*>(&smA[(arow0      + l15) * S3 + kc * 32 + quad * 8]);
        bf16x8 a1 = *reinterpret_cast<const bf16x8*>(&smA[(arow0 + 16 + l15) * S3 + kc * 32 + quad * 8]);
        bf16x8 b = *reinterpret_cast<const bf16x8*>(&w4_f[((kc * 2 + wc) * 64 + lane) * 8]);
        acc4[0] = __builtin_amdgcn_mfma_f32_16x16x32_bf16(a0, b, acc4[0], 0, 0, 0);
        acc4[1] = __builtin_amdgcn_mfma_f32_16x16x32_bf16(a1, b, acc4[1], 0, 0, 0);
    }
    {
        int o = wc * 16 + l15;
        float bb = b4[o], wv = w5[o];
        float part[2][4];
#pragma unroll
        for (int rt = 0; rt < 2; ++rt)
#pragma unroll
            for (int r = 0; r < 4; ++r)
                part[rt][r] = fmaxf(acc4[rt][r] + bb, 0.f) * wv;
#pragma unroll
        for (int mask = 1; mask < 16; mask <<= 1)
#pragma unroll
            for (int rt = 0; rt < 2; ++rt)
#pragma unroll
                for (int r = 0; r < 4; ++r)
                    part[rt][r] += __shfl_xor(part[rt][r], mask, 64);
        if (l15 == 0)
#pragma unroll
            for (int rt = 0; rt < 2; ++rt)
#pragma unroll
                for (int r = 0; r < 4; ++r) {
                    int m = arow0 + rt * 16 + quad * 4 + r;
                    s_l5[m][wc] = part[rt][r];
                }
    }
    __syncthreads();                                          // B7
    if (tid < 64) {
        int j = j0 + tid;
        float v = s_l5[tid][0] + s_l5[tid][1] + b5[0];
        out[i * 768 + j] = (j == i) ? -1.0e9f : v;
    }
}

// ---------------------------------------------------------------------------
extern "C" void kernel_launch(void* const* d_in, const int* in_sizes, int n_in,
                              void* d_out, int out_size, void* d_ws, size_t ws_size,
                              hipStream_t stream)
{
    const float* features   = (const float*)d_in[0];
    const float* boxes      = (const float*)d_in[1];
    const float* in_proj_w  = (const float*)d_in[2];
    const float* in_proj_b  = (const float*)d_in[3];
    const float* out_proj_w = (const float*)d_in[4];
    const float* out_proj_b = (const float*)d_in[5];
    const float* w1  = (const float*)d_in[6];
    const float* b1  = (const float*)d_in[7];
    const float* ln_g = (const float*)d_in[8];
    const float* ln_b = (const float*)d_in[9];
    const float* w2  = (const float*)d_in[10];
    const float* b2  = (const float*)d_in[11];
    const float* w3  = (const float*)d_in[12];
    const float* b3  = (const float*)d_in[13];
    const float* w4  = (const float*)d_in[14];
    const float* b4  = (const float*)d_in[15];
    const float* w5  = (const float*)d_in[16];
    const float* b5  = (const float*)d_in[17];
    float* out = (float*)d_out;

    // ---- workspace layout ----
    char* p = (char*)d_ws;
    unsigned short* qkvb = (unsigned short*)p; p += 768 * 768 * 2;
    unsigned short* Vt   = (unsigned short*)p; p += 256 * 768 * 2;
    unsigned short* Obf  = (unsigned short*)p; p += 768 * 256 * 2;
    unsigned short* attb = (unsigned short*)p; p += 768 * 256 * 2;
    float* att   = (float*)p; p += 768 * 256 * 4;
    float* Aonly = (float*)p; p += 768 * 256 * 4;
    unsigned short* Btb  = (unsigned short*)p; p += 256 * 768 * 2;
    unsigned short* featb = (unsigned short*)p; p += 196608 * 2;
    unsigned short* inWb  = (unsigned short*)p; p += 196608 * 2;
    unsigned short* outWb = (unsigned short*)p; p += 65536 * 2;
    unsigned short* wABb  = (unsigned short*)p; p += 131072 * 2;
    unsigned short* w1c_f = (unsigned short*)p; p += 65536 * 2;
    unsigned short* w2g_f = (unsigned short*)p; p += 32768 * 2;
    unsigned short* w3_f  = (unsigned short*)p; p += 8192 * 2;
    unsigned short* w4_f  = (unsigned short*)p; p += 2048 * 2;
    float* biasAB = (float*)p; p += 512 * 4;
    float* w1s_p  = (float*)p; p += 768 * 4;
    float* c1v    = (float*)p; p += 128 * 4;
    float* c2v    = (float*)p; p += 128 * 4;

    pack_all<<<dim3(2734), dim3(256), 0, stream>>>(features, in_proj_w,
        out_proj_w, w1, w2, w3, w4, b1, ln_g, ln_b, b2,
        featb, inWb, outWb, wABb, w1c_f, w2g_f, w3_f, w4_f,
        biasAB, w1s_p, c1v, c2v);
    // qkv: Q,K rows -> qkvb; V columns (>=512) transposed -> Vt
    gemm_bf<<<dim3(12, 12), dim3(256), 0, stream>>>(featb, inWb, in_proj_b,
        (float*)nullptr, qkvb, Vt, 768, 256, 768, 512);
    attn_mfma<<<dim3(8, 12), dim3(256), 0, stream>>>(qkvb, Vt, Obf);
    // att = O @ out_proj^T + b  (fp32 + bf16)
    gemm_bf<<<dim3(12, 4), dim3(256), 0, stream>>>(Obf, outWb, out_proj_b,
        att, attb, (unsigned short*)nullptr, 256, 256, 256, 1 << 30);
    // [A | B] = att @ [w1a;w1b]^T + [b1;0]; A (cols<256) -> Aonly fp32,
    // B (cols>=256) -> Btb transposed bf16
    gemm_bf<<<dim3(12, 8), dim3(256), 0, stream>>>(attb, wABb, biasAB,
        Aonly, (unsigned short*)nullptr, Btb, 512, 256, 256, 256);
    pair_mlp<<<dim3(768, 12), dim3(256), 0, stream>>>(att, attb, Aonly, Btb,
        w1c_f, w2g_f, w3_f, w4_f, w1s_p, boxes, c1v, c2v,
        b3, b4, w5, b5, out);
}

// Round 5
// 327.095 us; speedup vs baseline: 1.1560x; 1.1560x over previous
//
#include <hip/hip_runtime.h>

// ---------------------------------------------------------------------------
// ImprovedLinkingPredictor round 5: transposed pair-MLP pipeline.
// All pair-MLP GEMMs compute D^T = W @ act^T  (A-operand = weights from
// global frag-major tables, B-operand = activations in LDS). Each thread
// ends up owning 4 consecutive feature dims for one j => vectorized (b64)
// LDS writes, float4 epilogue constant loads, 2-step quad reductions.
// ---------------------------------------------------------------------------

typedef __attribute__((ext_vector_type(8))) __bf16 bf16x8;   // MFMA A/B frag
typedef __attribute__((ext_vector_type(4))) float f32x4;     // MFMA C/D frag

__device__ __forceinline__ float bf2f(unsigned short u) {
    return __uint_as_float(((unsigned int)u) << 16);
}
__device__ __forceinline__ unsigned short f2bf(float f) {
    union { __bf16 b; unsigned short u; } cv;
    cv.b = (__bf16)f;
    return cv.u;
}
__device__ __forceinline__ unsigned pk2(float lo, float hi) {
    return (unsigned)f2bf(lo) | ((unsigned)f2bf(hi) << 16);
}

// ---------------- pack: bf16 casts + fragment-major weight layouts ----------
// frag-major mapping (same function serves A- or B-operand roles):
// elem (o,k) of W[N][K] at ((kc*NT + (o>>4))*64 + lane)*8 + e,
// lane = (o&15) | (((k>>3)&3)<<4), e = k&7, kc = k>>5.
__global__ __launch_bounds__(256) void pack_all(
    const float* __restrict__ features, const float* __restrict__ in_proj_w,
    const float* __restrict__ out_proj_w, const float* __restrict__ w1,
    const float* __restrict__ w2, const float* __restrict__ w3,
    const float* __restrict__ w4, const float* __restrict__ b1,
    const float* __restrict__ ln_g, const float* __restrict__ ln_b,
    const float* __restrict__ b2,
    unsigned short* __restrict__ featb, unsigned short* __restrict__ inWb,
    unsigned short* __restrict__ outWb, unsigned short* __restrict__ wABb,
    unsigned short* __restrict__ w1c_f, unsigned short* __restrict__ w2g_f,
    unsigned short* __restrict__ w3_f, unsigned short* __restrict__ w4_f,
    float* __restrict__ biasAB, float* __restrict__ w1s_p,
    float* __restrict__ c1, float* __restrict__ c2)
{
    int t = blockIdx.x * 256 + threadIdx.x;
    if (t < 196608) {
        featb[t] = f2bf(features[t]);
    } else if (t < 393216) {
        int u = t - 196608; inWb[u] = f2bf(in_proj_w[u]);
    } else if (t < 458752) {
        int u = t - 393216; outWb[u] = f2bf(out_proj_w[u]);
    } else if (t < 589824) {                  // wABb = [w1a ; w1b] rows
        int u = t - 458752; int n = u >> 8, k = u & 255;
        float v = (n < 256) ? w1[n * 771 + k] : w1[(n - 256) * 771 + 256 + k];
        wABb[u] = f2bf(v);
    } else if (t < 655360) {                  // w1c_f (frag-major, K=256,N=256)
        int u = t - 589824;
        int e = u & 7, lane = (u >> 3) & 63, f = u >> 9;
        int l15 = lane & 15, quad = lane >> 4;
        int ct = f & 15, kc = f >> 4;
        int o = ct * 16 + l15, k = kc * 32 + quad * 8 + e;
        w1c_f[u] = f2bf(w1[o * 771 + 512 + k]);
    } else if (t < 688128) {                  // w2g_f = (w2 * ln_g) frag-major
        int u = t - 655360;
        int e = u & 7, lane = (u >> 3) & 63, f = u >> 9;
        int l15 = lane & 15, quad = lane >> 4;
        int ct = f & 7, kc = f >> 3;
        int o = ct * 16 + l15, k = kc * 32 + quad * 8 + e;
        w2g_f[u] = f2bf(w2[o * 256 + k] * ln_g[k]);
    } else if (t < 696320) {                  // w3_f (K=128,N=64)
        int u = t - 688128;
        int e = u & 7, lane = (u >> 3) & 63, f = u >> 9;
        int l15 = lane & 15, quad = lane >> 4;
        int ct = f & 3, kc = f >> 2;
        int o = ct * 16 + l15, k = kc * 32 + quad * 8 + e;
        w3_f[u] = f2bf(w3[o * 128 + k]);
    } else if (t < 698368) {                  // w4_f (K=64,N=32)
        int u = t - 696320;
        int e = u & 7, lane = (u >> 3) & 63, f = u >> 9;
        int l15 = lane & 15, quad = lane >> 4;
        int ct = f & 1, kc = f >> 1;
        int o = ct * 16 + l15, k = kc * 32 + quad * 8 + e;
        w4_f[u] = f2bf(w4[o * 64 + k]);
    } else if (t < 698880) {                  // biasAB
        int u = t - 698368;
        biasAB[u] = (u < 256) ? b1[u] : 0.0f;
    } else if (t < 699648) {                  // w1s_p[s*256+o]
        int u = t - 698880;
        int s = u >> 8, o = u & 255;
        w1s_p[u] = w1[o * 771 + 768 + s];
    } else if (t < 699776) {                  // c1/c2 (LN folding constants)
        int p = t - 699648;
        float s2 = 0.f, s1 = 0.f;
        for (int k = 0; k < 256; k += 4) {
            float4 w = *reinterpret_cast<const float4*>(&w2[p * 256 + k]);
            float4 g = *reinterpret_cast<const float4*>(&ln_g[k]);
            float4 lb = *reinterpret_cast<const float4*>(&ln_b[k]);
            s2 += g.x * w.x + g.y * w.y + g.z * w.z + g.w * w.w;
            s1 += lb.x * w.x + lb.y * w.y + lb.z * w.z + lb.w * w.w;
        }
        c2[p] = s2;
        c1[p] = s1 + b2[p];
    }
}

// ---------------- bf16 MFMA GEMM: C[M,N] = A[M,K] @ W[N,K]^T + bias --------
__global__ __launch_bounds__(256) void gemm_bf(
    const unsigned short* __restrict__ A, const unsigned short* __restrict__ W,
    const float* __restrict__ bias, float* __restrict__ Cf,
    unsigned short* __restrict__ Cbf, unsigned short* __restrict__ Vt,
    int N, int K, int ldc, int tcol0)
{
    const int wv = threadIdx.x >> 6, lane = threadIdx.x & 63;
    const int l15 = lane & 15, quad = lane >> 4;
    const int row0 = blockIdx.x * 64 + wv * 16;
    const int col0 = blockIdx.y * 64;
    f32x4 acc[4] = {};
    for (int kc = 0; kc < (K >> 5); ++kc) {
        bf16x8 a = *reinterpret_cast<const bf16x8*>(&A[(row0 + l15) * K + kc * 32 + quad * 8]);
#pragma unroll
        for (int ct = 0; ct < 4; ++ct) {
            bf16x8 b = *reinterpret_cast<const bf16x8*>(&W[(col0 + ct * 16 + l15) * K + kc * 32 + quad * 8]);
            acc[ct] = __builtin_amdgcn_mfma_f32_16x16x32_bf16(a, b, acc[ct], 0, 0, 0);
        }
    }
#pragma unroll
    for (int ct = 0; ct < 4; ++ct)
#pragma unroll
        for (int r = 0; r < 4; ++r) {
            int row = row0 + quad * 4 + r, col = col0 + ct * 16 + l15;
            float v = acc[ct][r] + bias[col];
            if (Vt && col >= tcol0) {
                Vt[(col - tcol0) * 768 + row] = f2bf(v);
            } else {
                if (Cf)  Cf[row * ldc + col] = v;
                if (Cbf) Cbf[row * ldc + col] = f2bf(v);
            }
        }
}

// ---------------- fused MFMA attention -------------------------------------
#define SP 776

__global__ __launch_bounds__(256) void attn_mfma(
    const unsigned short* __restrict__ qkvb, const unsigned short* __restrict__ Vt,
    unsigned short* __restrict__ Obf)
{
    __shared__ __align__(16) unsigned short smS[64 * SP];
    const int h = blockIdx.x, q0 = blockIdx.y * 64, hb = h * 32;
    const int tid = threadIdx.x, wave = tid >> 6, lane = tid & 63;
    const int l15 = lane & 15, quad = lane >> 4;

    bf16x8 af[4];
#pragma unroll
    for (int mt = 0; mt < 4; ++mt)
        af[mt] = *reinterpret_cast<const bf16x8*>(&qkvb[(q0 + mt * 16 + l15) * 768 + hb + quad * 8]);
#pragma unroll
    for (int ct = 0; ct < 12; ++ct) {
        int n0 = wave * 192 + ct * 16;
        bf16x8 b = *reinterpret_cast<const bf16x8*>(&qkvb[(n0 + l15) * 768 + 256 + hb + quad * 8]);
#pragma unroll
        for (int mt = 0; mt < 4; ++mt) {
            f32x4 c = {};
            c = __builtin_amdgcn_mfma_f32_16x16x32_bf16(af[mt], b, c, 0, 0, 0);
#pragma unroll
            for (int r = 0; r < 4; ++r)
                smS[(mt * 16 + quad * 4 + r) * SP + n0 + l15] =
                    f2bf(c[r] * 0.17677669529663689f);
        }
    }
    __syncthreads();

    {   // row softmax: 4 threads per row, 192 cols each
        const int row = tid >> 2, part = tid & 3;
        unsigned short* rp = &smS[row * SP + part * 192];
        float mx = -3.0e38f;
#pragma unroll
        for (int c8 = 0; c8 < 24; ++c8) {
            uint4 v = *reinterpret_cast<const uint4*>(&rp[c8 * 8]);
            const unsigned short* pe = reinterpret_cast<const unsigned short*>(&v);
#pragma unroll
            for (int e = 0; e < 8; ++e) mx = fmaxf(mx, bf2f(pe[e]));
        }
        mx = fmaxf(mx, __shfl_xor(mx, 1, 64));
        mx = fmaxf(mx, __shfl_xor(mx, 2, 64));
        float ls = 0.f;
#pragma unroll
        for (int c8 = 0; c8 < 24; ++c8) {
            uint4 v = *reinterpret_cast<const uint4*>(&rp[c8 * 8]);
            const unsigned short* pe = reinterpret_cast<const unsigned short*>(&v);
            unsigned short o8[8];
#pragma unroll
            for (int e = 0; e < 8; ++e) {
                float ev = __expf(bf2f(pe[e]) - mx);
                ls += ev;
                o8[e] = f2bf(ev);
            }
            *reinterpret_cast<uint4*>(&rp[c8 * 8]) = *reinterpret_cast<const uint4*>(o8);
        }
        ls += __shfl_xor(ls, 1, 64);
        ls += __shfl_xor(ls, 2, 64);
        float inv = 1.0f / ls;
#pragma unroll
        for (int c8 = 0; c8 < 24; ++c8) {
            uint4 v = *reinterpret_cast<const uint4*>(&rp[c8 * 8]);
            const unsigned short* pe = reinterpret_cast<const unsigned short*>(&v);
            unsigned short o8[8];
#pragma unroll
            for (int e = 0; e < 8; ++e) o8[e] = f2bf(bf2f(pe[e]) * inv);
            *reinterpret_cast<uint4*>(&rp[c8 * 8]) = *reinterpret_cast<const uint4*>(o8);
        }
    }
    f32x4 accp[2] = {};
    for (int kc = 0; kc < 24; ++kc) {
        bf16x8 a = *reinterpret_cast<const bf16x8*>(&smS[(wave * 16 + l15) * SP + kc * 32 + quad * 8]);
#pragma unroll
        for (int ct = 0; ct < 2; ++ct) {
            bf16x8 b = *reinterpret_cast<const bf16x8*>(&Vt[(hb + ct * 16 + l15) * 768 + kc * 32 + quad * 8]);
            accp[ct] = __builtin_amdgcn_mfma_f32_16x16x32_bf16(a, b, accp[ct], 0, 0, 0);
        }
    }
#pragma unroll
    for (int ct = 0; ct < 2; ++ct)
#pragma unroll
        for (int r = 0; r < 4; ++r) {
            int row = q0 + wave * 16 + quad * 4 + r;
            Obf[row * 256 + hb + ct * 16 + l15] = f2bf(accp[ct][r]);
        }
}

// ---------------- fused pair MLP (transposed), 1 i x 64 j ------------------
#define S1 264   // h1 row stride (shorts), rows indexed by j
#define S2 136
#define S3 72

__global__ __launch_bounds__(256, 4) void pair_mlp(
    const float* __restrict__ att, const unsigned short* __restrict__ attb,
    const float* __restrict__ AB,
    const unsigned short* __restrict__ w1c_f, const unsigned short* __restrict__ w2g_f,
    const unsigned short* __restrict__ w3_f, const unsigned short* __restrict__ w4_f,
    const float* __restrict__ w1s_p, const float* __restrict__ boxes,
    const float* __restrict__ c1, const float* __restrict__ c2,
    const float* __restrict__ b3, const float* __restrict__ b4,
    const float* __restrict__ w5, const float* __restrict__ b5,
    float* __restrict__ out)
{
    __shared__ __align__(16) unsigned short smH[64 * S1];    // 33.8 KB, reused
    __shared__ float s_xd[64], s_ayd[64], s_yd[64];
    __shared__ float s_psum[64][4], s_pssq[64][4];
    __shared__ float s_mu[64], s_rs[64];
    __shared__ float s_l5[64][2];

    const int i    = blockIdx.x;
    const int j0   = blockIdx.y * 64;
    const int tid  = threadIdx.x;
    const int wave = tid >> 6;
    const int lane = tid & 63;
    const int l15  = lane & 15;
    const int quad = lane >> 4;

    if (tid < 64) {
        int j = j0 + tid;
        float xd = fabsf(boxes[i * 4 + 0] - boxes[j * 4 + 0]);
        float yd = boxes[i * 4 + 1] - boxes[j * 4 + 1];
        s_xd[tid] = xd; s_yd[tid] = yd; s_ayd[tid] = fabsf(yd);
    }
    // stage scaledA[j][d] = bf16(att_j[d] * att_i[d])  (64 x 256)
#pragma unroll
    for (int it = 0; it < 8; ++it) {
        int c = tid + it * 256;
        int r = c >> 5, cc = (c & 31) << 3;
        uint4 v = *reinterpret_cast<const uint4*>(&attb[(j0 + r) * 256 + cc]);
        const unsigned short* pj = reinterpret_cast<const unsigned short*>(&v);
        float4 A0 = *reinterpret_cast<const float4*>(&att[i * 256 + cc]);
        float4 A1 = *reinterpret_cast<const float4*>(&att[i * 256 + cc + 4]);
        float ai[8] = {A0.x, A0.y, A0.z, A0.w, A1.x, A1.y, A1.z, A1.w};
        unsigned short o8[8];
#pragma unroll
        for (int e = 0; e < 8; ++e) o8[e] = f2bf(bf2f(pj[e]) * ai[e]);
        *reinterpret_cast<uint4*>(&smH[r * S1 + cc]) = *reinterpret_cast<const uint4*>(o8);
    }
    __syncthreads();                                          // B0: scaledA ready

    // ======== GEMM1^T: D1[o][j] = w1c[o][:] . scaledA[j][:], o-slice/wave ===
    f32x4 acc1[4][4] = {};   // [mt (o 16-tile)][nt (j 16-tile)]
    for (int kc = 0; kc < 8; ++kc) {
        bf16x8 a[4];
#pragma unroll
        for (int mt = 0; mt < 4; ++mt)
            a[mt] = *reinterpret_cast<const bf16x8*>(&w1c_f[((kc * 16 + wave * 4 + mt) * 64 + lane) * 8]);
#pragma unroll
        for (int nt = 0; nt < 4; ++nt) {
            bf16x8 b = *reinterpret_cast<const bf16x8*>(&smH[(nt * 16 + l15) * S1 + kc * 32 + quad * 8]);
#pragma unroll
            for (int mt = 0; mt < 4; ++mt)
                acc1[mt][nt] = __builtin_amdgcn_mfma_f32_16x16x32_bf16(a[mt], b, acc1[mt][nt], 0, 0, 0);
        }
    }

    // ---- epilogue1: + A_i[o] + B_j[o] + spatial, relu, stats ----
    const int o0 = wave * 64;
    float vsum[4] = {}, vssq[4] = {};
#pragma unroll
    for (int mt = 0; mt < 4; ++mt) {
        int o = o0 + mt * 16 + quad * 4;
        float4 Ai = *reinterpret_cast<const float4*>(&AB[i * 512 + o]);
        float4 W0 = *reinterpret_cast<const float4*>(&w1s_p[o]);
        float4 W1 = *reinterpret_cast<const float4*>(&w1s_p[256 + o]);
        float4 W2 = *reinterpret_cast<const float4*>(&w1s_p[512 + o]);
        float AiA[4] = {Ai.x, Ai.y, Ai.z, Ai.w};
        float W0A[4] = {W0.x, W0.y, W0.z, W0.w};
        float W1A[4] = {W1.x, W1.y, W1.z, W1.w};
        float W2A[4] = {W2.x, W2.y, W2.z, W2.w};
#pragma unroll
        for (int nt = 0; nt < 4; ++nt) {
            int j = nt * 16 + l15;
            float4 Bj = *reinterpret_cast<const float4*>(&AB[(j0 + j) * 512 + 256 + o]);
            float BjA[4] = {Bj.x, Bj.y, Bj.z, Bj.w};
            float xd = s_xd[j], ayd = s_ayd[j], yd = s_yd[j];
#pragma unroll
            for (int r = 0; r < 4; ++r) {
                float v = acc1[mt][nt][r] + AiA[r] + BjA[r]
                        + xd * W0A[r] + ayd * W1A[r] + yd * W2A[r];
                v = fmaxf(v, 0.f);
                acc1[mt][nt][r] = v;
                vsum[nt] += v; vssq[nt] += v * v;
            }
        }
    }
#pragma unroll
    for (int nt = 0; nt < 4; ++nt) {
        vsum[nt] += __shfl_xor(vsum[nt], 16, 64);
        vsum[nt] += __shfl_xor(vsum[nt], 32, 64);
        vssq[nt] += __shfl_xor(vssq[nt], 16, 64);
        vssq[nt] += __shfl_xor(vssq[nt], 32, 64);
    }
    if (quad == 0)
#pragma unroll
        for (int nt = 0; nt < 4; ++nt) {
            s_psum[nt * 16 + l15][wave] = vsum[nt];
            s_pssq[nt * 16 + l15][wave] = vssq[nt];
        }
    __syncthreads();                                          // B1: smH reads done
    // h1^T write: [j][o], 4 contiguous o per store -> ds_write_b64
#pragma unroll
    for (int mt = 0; mt < 4; ++mt) {
        int o = o0 + mt * 16 + quad * 4;
#pragma unroll
        for (int nt = 0; nt < 4; ++nt) {
            int j = nt * 16 + l15;
            uint2 w;
            w.x = pk2(acc1[mt][nt][0], acc1[mt][nt][1]);
            w.y = pk2(acc1[mt][nt][2], acc1[mt][nt][3]);
            *reinterpret_cast<uint2*>(&smH[j * S1 + o]) = w;
        }
    }
    if (wave == 0) {   // finalize LN stats
        int j = lane;
        float sm = (s_psum[j][0] + s_psum[j][1] + s_psum[j][2] + s_psum[j][3]) * (1.0f / 256.0f);
        float sq = (s_pssq[j][0] + s_pssq[j][1] + s_pssq[j][2] + s_pssq[j][3]) * (1.0f / 256.0f);
        s_mu[j] = sm;
        s_rs[j] = rsqrtf(sq - sm * sm + 1e-5f);
    }
    __syncthreads();                                          // B2: h1 + stats ready

    // ======== GEMM2^T: D2[p][j] = w2g[p][:] . h1[j][:] ========
    f32x4 acc2[2][4] = {};
    for (int kc = 0; kc < 8; ++kc) {
        bf16x8 a[2];
#pragma unroll
        for (int mt = 0; mt < 2; ++mt)
            a[mt] = *reinterpret_cast<const bf16x8*>(&w2g_f[((kc * 8 + wave * 2 + mt) * 64 + lane) * 8]);
#pragma unroll
        for (int nt = 0; nt < 4; ++nt) {
            bf16x8 b = *reinterpret_cast<const bf16x8*>(&smH[(nt * 16 + l15) * S1 + kc * 32 + quad * 8]);
#pragma unroll
            for (int mt = 0; mt < 2; ++mt)
                acc2[mt][nt] = __builtin_amdgcn_mfma_f32_16x16x32_bf16(a[mt], b, acc2[mt][nt], 0, 0, 0);
        }
    }
    __syncthreads();                                          // B3: h1 reads done
    // epilogue2: LN-folded affine + relu -> h2^T[j][p]
#pragma unroll
    for (int mt = 0; mt < 2; ++mt) {
        int p = wave * 32 + mt * 16 + quad * 4;
        float4 C1 = *reinterpret_cast<const float4*>(&c1[p]);
        float4 C2 = *reinterpret_cast<const float4*>(&c2[p]);
        float C1A[4] = {C1.x, C1.y, C1.z, C1.w};
        float C2A[4] = {C2.x, C2.y, C2.z, C2.w};
#pragma unroll
        for (int nt = 0; nt < 4; ++nt) {
            int j = nt * 16 + l15;
            float mu = s_mu[j], rs = s_rs[j];
            float vv[4];
#pragma unroll
            for (int r = 0; r < 4; ++r)
                vv[r] = fmaxf(rs * (acc2[mt][nt][r] - mu * C2A[r]) + C1A[r], 0.f);
            uint2 w;
            w.x = pk2(vv[0], vv[1]);
            w.y = pk2(vv[2], vv[3]);
            *reinterpret_cast<uint2*>(&smH[j * S2 + p]) = w;
        }
    }
    __syncthreads();                                          // B4: h2 ready

    // ======== GEMM3^T: D3[q][j] = w3[q][:] . h2[j][:] ========
    f32x4 acc3[4] = {};
    for (int kc = 0; kc < 4; ++kc) {
        bf16x8 a = *reinterpret_cast<const bf16x8*>(&w3_f[((kc * 4 + wave) * 64 + lane) * 8]);
#pragma unroll
        for (int nt = 0; nt < 4; ++nt) {
            bf16x8 b = *reinterpret_cast<const bf16x8*>(&smH[(nt * 16 + l15) * S2 + kc * 32 + quad * 8]);
            acc3[nt] = __builtin_amdgcn_mfma_f32_16x16x32_bf16(a, b, acc3[nt], 0, 0, 0);
        }
    }
    __syncthreads();                                          // B5: h2 reads done
    {
        int q = wave * 16 + quad * 4;
        float4 B3 = *reinterpret_cast<const float4*>(&b3[q]);
        float B3A[4] = {B3.x, B3.y, B3.z, B3.w};
#pragma unroll
        for (int nt = 0; nt < 4; ++nt) {
            int j = nt * 16 + l15;
            float vv[4];
#pragma unroll
            for (int r = 0; r < 4; ++r)
                vv[r] = fmaxf(acc3[nt][r] + B3A[r], 0.f);
            uint2 w;
            w.x = pk2(vv[0], vv[1]);
            w.y = pk2(vv[2], vv[3]);
            *reinterpret_cast<uint2*>(&smH[j * S3 + q]) = w;
        }
    }
    __syncthreads();                                          // B6: h3 ready

    // ======== GEMM4^T + head ========
    const int mt4 = wave & 1;        // o4 16-tile
    const int jh  = wave >> 1;       // j 32-half
    f32x4 acc4[2] = {};
#pragma unroll
    for (int kc = 0; kc < 2; ++kc) {
        bf16x8 a = *reinterpret_cast<const bf16x8*>(&w4_f[((kc * 2 + mt4) * 64 + lane) * 8]);
#pragma unroll
        for (int nt = 0; nt < 2; ++nt) {
            int j = jh * 32 + nt * 16 + l15;
            bf16x8 b = *reinterpret_cast<const bf16x8*>(&smH[j * S3 + kc * 32 + quad * 8]);
            acc4[nt] = __builtin_amdgcn_mfma_f32_16x16x32_bf16(a, b, acc4[nt], 0, 0, 0);
        }
    }
    {
        int o4 = mt4 * 16 + quad * 4;
        float4 B4 = *reinterpret_cast<const float4*>(&b4[o4]);
        float4 W5 = *reinterpret_cast<const float4*>(&w5[o4]);
        float B4A[4] = {B4.x, B4.y, B4.z, B4.w};
        float W5A[4] = {W5.x, W5.y, W5.z, W5.w};
#pragma unroll
        for (int nt = 0; nt < 2; ++nt) {
            float part = 0.f;
#pragma unroll
            for (int r = 0; r < 4; ++r)
                part += fmaxf(acc4[nt][r] + B4A[r], 0.f) * W5A[r];
            part += __shfl_xor(part, 16, 64);
            part += __shfl_xor(part, 32, 64);
            if (quad == 0)
                s_l5[jh * 32 + nt * 16 + l15][mt4] = part;
        }
    }
    __syncthreads();                                          // B7
    if (tid < 64) {
        int j = j0 + tid;
        float v = s_l5[tid][0] + s_l5[tid][1] + b5[0];
        out[i * 768 + j] = (j == i) ? -1.0e9f : v;
    }
}

// ---------------------------------------------------------------------------
extern "C" void kernel_launch(void* const* d_in, const int* in_sizes, int n_in,
                              void* d_out, int out_size, void* d_ws, size_t ws_size,
                              hipStream_t stream)
{
    const float* features   = (const float*)d_in[0];
    const float* boxes      = (const float*)d_in[1];
    const float* in_proj_w  = (const float*)d_in[2];
    const float* in_proj_b  = (const float*)d_in[3];
    const float* out_proj_w = (const float*)d_in[4];
    const float* out_proj_b = (const float*)d_in[5];
    const float* w1  = (const float*)d_in[6];
    const float* b1  = (const float*)d_in[7];
    const float* ln_g = (const float*)d_in[8];
    const float* ln_b = (const float*)d_in[9];
    const float* w2  = (const float*)d_in[10];
    const float* b2  = (const float*)d_in[11];
    const float* w3  = (const float*)d_in[12];
    const float* b3  = (const float*)d_in[13];
    const float* w4  = (const float*)d_in[14];
    const float* b4  = (const float*)d_in[15];
    const float* w5  = (const float*)d_in[16];
    const float* b5  = (const float*)d_in[17];
    float* out = (float*)d_out;

    // ---- workspace layout ----
    char* p = (char*)d_ws;
    unsigned short* qkvb = (unsigned short*)p; p += 768 * 768 * 2;
    unsigned short* Vt   = (unsigned short*)p; p += 256 * 768 * 2;
    unsigned short* Obf  = (unsigned short*)p; p += 768 * 256 * 2;
    unsigned short* attb = (unsigned short*)p; p += 768 * 256 * 2;
    float* att = (float*)p; p += 768 * 256 * 4;
    float* AB  = (float*)p; p += 768 * 512 * 4;
    unsigned short* featb = (unsigned short*)p; p += 196608 * 2;
    unsigned short* inWb  = (unsigned short*)p; p += 196608 * 2;
    unsigned short* outWb = (unsigned short*)p; p += 65536 * 2;
    unsigned short* wABb  = (unsigned short*)p; p += 131072 * 2;
    unsigned short* w1c_f = (unsigned short*)p; p += 65536 * 2;
    unsigned short* w2g_f = (unsigned short*)p; p += 32768 * 2;
    unsigned short* w3_f  = (unsigned short*)p; p += 8192 * 2;
    unsigned short* w4_f  = (unsigned short*)p; p += 2048 * 2;
    float* biasAB = (float*)p; p += 512 * 4;
    float* w1s_p  = (float*)p; p += 768 * 4;
    float* c1v    = (float*)p; p += 128 * 4;
    float* c2v    = (float*)p; p += 128 * 4;

    pack_all<<<dim3(2734), dim3(256), 0, stream>>>(features, in_proj_w,
        out_proj_w, w1, w2, w3, w4, b1, ln_g, ln_b, b2,
        featb, inWb, outWb, wABb, w1c_f, w2g_f, w3_f, w4_f,
        biasAB, w1s_p, c1v, c2v);
    gemm_bf<<<dim3(12, 12), dim3(256), 0, stream>>>(featb, inWb, in_proj_b,
        (float*)nullptr, qkvb, Vt, 768, 256, 768, 512);
    attn_mfma<<<dim3(8, 12), dim3(256), 0, stream>>>(qkvb, Vt, Obf);
    gemm_bf<<<dim3(12, 4), dim3(256), 0, stream>>>(Obf, outWb, out_proj_b,
        att, attb, (unsigned short*)nullptr, 256, 256, 256, 1 << 30);
    // AB = att @ [w1a;w1b]^T + [b1;0]  (fp32, row-major 768x512)
    gemm_bf<<<dim3(12, 8), dim3(256), 0, stream>>>(attb, wABb, biasAB,
        AB, (unsigned short*)nullptr, (unsigned short*)nullptr, 512, 256, 512, 1 << 30);
    pair_mlp<<<dim3(768, 12), dim3(256), 0, stream>>>(att, attb, AB,
        w1c_f, w2g_f, w3_f, w4_f, w1s_p, boxes, c1v, c2v,
        b3, b4, w5, b5, out);
}

// Round 6
// 304.693 us; speedup vs baseline: 1.2410x; 1.0735x over previous
//
#include <hip/hip_runtime.h>

// ---------------------------------------------------------------------------
// ImprovedLinkingPredictor round 6: fp8-internal transposed pair MLP.
// - All pair-MLP GEMMs in fp8 e4m3 (OCP, gfx950): halves LDS traffic/footprint.
// - Spatial terms folded into GEMM1 (K=288: [att_i.*att_j | xd,|yd|,yd,0..]).
// - Front-end: AB = O @ Wcomb^T with Wcomb = wAB@outW precomputed, so one
//   fused [att|AB] GEMM replaces the two dependent post-attention GEMMs.
// ---------------------------------------------------------------------------

typedef __attribute__((ext_vector_type(8))) __bf16 bf16x8;   // bf16 MFMA frag
typedef __attribute__((ext_vector_type(4))) float f32x4;     // MFMA C/D frag

__device__ __forceinline__ float bf2f(unsigned short u) {
    return __uint_as_float(((unsigned int)u) << 16);
}
__device__ __forceinline__ unsigned short f2bf(float f) {
    union { __bf16 b; unsigned short u; } cv;
    cv.b = (__bf16)f;
    return cv.u;
}
__device__ __forceinline__ int pk4_fp8(float a, float b, float c, float d) {
    int w = __builtin_amdgcn_cvt_pk_fp8_f32(a, b, 0, false);
    w = __builtin_amdgcn_cvt_pk_fp8_f32(c, d, w, true);
    return w;
}
__device__ __forceinline__ unsigned char f2fp8(float v) {
    return (unsigned char)(__builtin_amdgcn_cvt_pk_fp8_f32(v, 0.f, 0, false) & 0xff);
}

// ---------------- pack: bf16/fp8 casts + fragment-major weight tables -------
// fp8 frag-major: elem (o,k) of W[N][K] at ((kc*NT + (o>>4))*64 + lane)*8 + e,
// lane = (o&15) | (((k>>3)&3)<<4), e = k&7, kc = k>>5.
__global__ __launch_bounds__(256) void pack_all(
    const float* __restrict__ features, const float* __restrict__ in_proj_w,
    const float* __restrict__ out_proj_w, const float* __restrict__ w1,
    const float* __restrict__ w2, const float* __restrict__ w3,
    const float* __restrict__ w4, const float* __restrict__ b1,
    const float* __restrict__ ln_g, const float* __restrict__ ln_b,
    const float* __restrict__ b2, const float* __restrict__ out_proj_b,
    unsigned short* __restrict__ featb, unsigned short* __restrict__ inWb,
    unsigned short* __restrict__ WcatB, unsigned short* __restrict__ outWTb,
    unsigned short* __restrict__ wABb,
    unsigned char* __restrict__ w1c_f8, unsigned char* __restrict__ w2g_f8,
    unsigned char* __restrict__ w3_f8, unsigned char* __restrict__ w4_f8,
    float* __restrict__ bias768, float* __restrict__ c1, float* __restrict__ c2,
    float* __restrict__ biasZ)
{
    int t = blockIdx.x * 256 + threadIdx.x;
    if (t < 196608) {                                   // featb
        featb[t] = f2bf(features[t]);
    } else if (t < 393216) {                            // inWb
        int u = t - 196608; inWb[u] = f2bf(in_proj_w[u]);
    } else if (t < 458752) {                            // WcatB rows 0..255 = outW
        int u = t - 393216; WcatB[u] = f2bf(out_proj_w[u]);
    } else if (t < 524288) {                            // outWTb = outW^T
        int u = t - 458752; int e = u >> 8, d = u & 255;
        outWTb[u] = f2bf(out_proj_w[d * 256 + e]);
    } else if (t < 655360) {                            // wABb = [w1a ; w1b]
        int u = t - 524288; int n = u >> 8, k = u & 255;
        float v = (n < 256) ? w1[n * 771 + k] : w1[(n - 256) * 771 + 256 + k];
        wABb[u] = f2bf(v);
    } else if (t < 729088) {                            // w1c_f8 K=288,N=256 (+spatial tail)
        int u = t - 655360;
        int e = u & 7, lane = (u >> 3) & 63, f = u >> 9;
        int l15 = lane & 15, quad = lane >> 4;
        int mt = f & 15, kc = f >> 4;                   // kc 0..8
        int o = mt * 16 + l15, k = kc * 32 + quad * 8 + e;
        float v;
        if (k < 256)            v = w1[o * 771 + 512 + k];
        else if (k < 259)       v = w1[o * 771 + 768 + (k - 256)];
        else                    v = 0.f;
        w1c_f8[u] = f2fp8(v);
    } else if (t < 761856) {                            // w2g_f8 = w2*ln_g, K=256,N=128
        int u = t - 729088;
        int e = u & 7, lane = (u >> 3) & 63, f = u >> 9;
        int l15 = lane & 15, quad = lane >> 4;
        int mt = f & 7, kc = f >> 3;
        int o = mt * 16 + l15, k = kc * 32 + quad * 8 + e;
        w2g_f8[u] = f2fp8(w2[o * 256 + k] * ln_g[k]);
    } else if (t < 770048) {                            // w3_f8 K=128,N=64
        int u = t - 761856;
        int e = u & 7, lane = (u >> 3) & 63, f = u >> 9;
        int l15 = lane & 15, quad = lane >> 4;
        int mt = f & 3, kc = f >> 2;
        int o = mt * 16 + l15, k = kc * 32 + quad * 8 + e;
        w3_f8[u] = f2fp8(w3[o * 128 + k]);
    } else if (t < 772096) {                            // w4_f8 K=64,N=32
        int u = t - 770048;
        int e = u & 7, lane = (u >> 3) & 63, f = u >> 9;
        int l15 = lane & 15, quad = lane >> 4;
        int mt = f & 1, kc = f >> 1;
        int o = mt * 16 + l15, k = kc * 32 + quad * 8 + e;
        w4_f8[u] = f2fp8(w4[o * 64 + k]);
    } else if (t < 772864) {                            // bias768
        int n = t - 772096;
        if (n < 256) bias768[n] = out_proj_b[n];
        else {
            int m = n - 256;
            float s = 0.f;
            for (int d = 0; d < 256; d += 4) {
                float4 ob = *reinterpret_cast<const float4*>(&out_proj_b[d]);
                const float* wr = (m < 256) ? &w1[m * 771 + d]
                                            : &w1[(m - 256) * 771 + 256 + d];
                float4 w = *reinterpret_cast<const float4*>(wr);
                s += ob.x * w.x + ob.y * w.y + ob.z * w.z + ob.w * w.w;
            }
            bias768[n] = s + ((m < 256) ? b1[m] : 0.f);
        }
    } else if (t < 772992) {                            // c1/c2 LN-fold constants
        int p = t - 772864;
        float s2 = 0.f, s1 = 0.f;
        for (int k = 0; k < 256; k += 4) {
            float4 w = *reinterpret_cast<const float4*>(&w2[p * 256 + k]);
            float4 g = *reinterpret_cast<const float4*>(&ln_g[k]);
            float4 lb = *reinterpret_cast<const float4*>(&ln_b[k]);
            s2 += g.x * w.x + g.y * w.y + g.z * w.z + g.w * w.w;
            s1 += lb.x * w.x + lb.y * w.y + lb.z * w.z + lb.w * w.w;
        }
        c2[p] = s2;
        c1[p] = s1 + b2[p];
    } else if (t < 773248) {                            // biasZ = zeros
        biasZ[t - 772992] = 0.f;
    }
}

// ---------------- bf16 MFMA GEMM: C[M,N] = A[M,K] @ W[N,K]^T + bias --------
__global__ __launch_bounds__(256) void gemm_bf(
    const unsigned short* __restrict__ A, const unsigned short* __restrict__ W,
    const float* __restrict__ bias, float* __restrict__ Cf,
    unsigned short* __restrict__ Cbf, unsigned short* __restrict__ Vt,
    int N, int K, int ldc, int tcol0)
{
    const int wv = threadIdx.x >> 6, lane = threadIdx.x & 63;
    const int l15 = lane & 15, quad = lane >> 4;
    const int row0 = blockIdx.x * 64 + wv * 16;
    const int col0 = blockIdx.y * 64;
    f32x4 acc[4] = {};
    for (int kc = 0; kc < (K >> 5); ++kc) {
        bf16x8 a = *reinterpret_cast<const bf16x8*>(&A[(row0 + l15) * K + kc * 32 + quad * 8]);
#pragma unroll
        for (int ct = 0; ct < 4; ++ct) {
            bf16x8 b = *reinterpret_cast<const bf16x8*>(&W[(col0 + ct * 16 + l15) * K + kc * 32 + quad * 8]);
            acc[ct] = __builtin_amdgcn_mfma_f32_16x16x32_bf16(a, b, acc[ct], 0, 0, 0);
        }
    }
#pragma unroll
    for (int ct = 0; ct < 4; ++ct)
#pragma unroll
        for (int r = 0; r < 4; ++r) {
            int row = row0 + quad * 4 + r, col = col0 + ct * 16 + l15;
            float v = acc[ct][r] + bias[col];
            if (Vt && col >= tcol0) {
                Vt[(col - tcol0) * 768 + row] = f2bf(v);
            } else {
                if (Cf)  Cf[row * ldc + col] = v;
                if (Cbf) Cbf[row * ldc + col] = f2bf(v);
            }
        }
}

// ---------------- fused [att | AB] GEMM ------------------------------------
// [att|AB] = O @ [outW ; Wcomb]^T + bias768. cols<256 -> att fp32 + attb bf16;
// cols>=256 -> AB fp32 (row stride 512).
__global__ __launch_bounds__(256) void gemm_attab(
    const unsigned short* __restrict__ A, const unsigned short* __restrict__ W,
    const float* __restrict__ bias, float* __restrict__ att,
    unsigned short* __restrict__ attb, float* __restrict__ AB)
{
    const int wv = threadIdx.x >> 6, lane = threadIdx.x & 63;
    const int l15 = lane & 15, quad = lane >> 4;
    const int row0 = blockIdx.x * 64 + wv * 16;
    const int col0 = blockIdx.y * 64;
    f32x4 acc[4] = {};
    for (int kc = 0; kc < 8; ++kc) {
        bf16x8 a = *reinterpret_cast<const bf16x8*>(&A[(row0 + l15) * 256 + kc * 32 + quad * 8]);
#pragma unroll
        for (int ct = 0; ct < 4; ++ct) {
            bf16x8 b = *reinterpret_cast<const bf16x8*>(&W[(col0 + ct * 16 + l15) * 256 + kc * 32 + quad * 8]);
            acc[ct] = __builtin_amdgcn_mfma_f32_16x16x32_bf16(a, b, acc[ct], 0, 0, 0);
        }
    }
#pragma unroll
    for (int ct = 0; ct < 4; ++ct)
#pragma unroll
        for (int r = 0; r < 4; ++r) {
            int row = row0 + quad * 4 + r, col = col0 + ct * 16 + l15;
            float v = acc[ct][r] + bias[col];
            if (col < 256) {
                att[row * 256 + col] = v;
                attb[row * 256 + col] = f2bf(v);
            } else {
                AB[row * 512 + (col - 256)] = v;
            }
        }
}

// ---------------- fused MFMA attention -------------------------------------
#define SP 776

__global__ __launch_bounds__(256) void attn_mfma(
    const unsigned short* __restrict__ qkvb, const unsigned short* __restrict__ Vt,
    unsigned short* __restrict__ Obf)
{
    __shared__ __align__(16) unsigned short smS[64 * SP];
    const int h = blockIdx.x, q0 = blockIdx.y * 64, hb = h * 32;
    const int tid = threadIdx.x, wave = tid >> 6, lane = tid & 63;
    const int l15 = lane & 15, quad = lane >> 4;

    bf16x8 af[4];
#pragma unroll
    for (int mt = 0; mt < 4; ++mt)
        af[mt] = *reinterpret_cast<const bf16x8*>(&qkvb[(q0 + mt * 16 + l15) * 768 + hb + quad * 8]);
#pragma unroll
    for (int ct = 0; ct < 12; ++ct) {
        int n0 = wave * 192 + ct * 16;
        bf16x8 b = *reinterpret_cast<const bf16x8*>(&qkvb[(n0 + l15) * 768 + 256 + hb + quad * 8]);
#pragma unroll
        for (int mt = 0; mt < 4; ++mt) {
            f32x4 c = {};
            c = __builtin_amdgcn_mfma_f32_16x16x32_bf16(af[mt], b, c, 0, 0, 0);
#pragma unroll
            for (int r = 0; r < 4; ++r)
                smS[(mt * 16 + quad * 4 + r) * SP + n0 + l15] =
                    f2bf(c[r] * 0.17677669529663689f);
        }
    }
    __syncthreads();

    {   // row softmax: 4 threads per row, 192 cols each
        const int row = tid >> 2, part = tid & 3;
        unsigned short* rp = &smS[row * SP + part * 192];
        float mx = -3.0e38f;
#pragma unroll
        for (int c8 = 0; c8 < 24; ++c8) {
            uint4 v = *reinterpret_cast<const uint4*>(&rp[c8 * 8]);
            const unsigned short* pe = reinterpret_cast<const unsigned short*>(&v);
#pragma unroll
            for (int e = 0; e < 8; ++e) mx = fmaxf(mx, bf2f(pe[e]));
        }
        mx = fmaxf(mx, __shfl_xor(mx, 1, 64));
        mx = fmaxf(mx, __shfl_xor(mx, 2, 64));
        float ls = 0.f;
#pragma unroll
        for (int c8 = 0; c8 < 24; ++c8) {
            uint4 v = *reinterpret_cast<const uint4*>(&rp[c8 * 8]);
            const unsigned short* pe = reinterpret_cast<const unsigned short*>(&v);
            unsigned short o8[8];
#pragma unroll
            for (int e = 0; e < 8; ++e) {
                float ev = __expf(bf2f(pe[e]) - mx);
                ls += ev;
                o8[e] = f2bf(ev);
            }
            *reinterpret_cast<uint4*>(&rp[c8 * 8]) = *reinterpret_cast<const uint4*>(o8);
        }
        ls += __shfl_xor(ls, 1, 64);
        ls += __shfl_xor(ls, 2, 64);
        float inv = 1.0f / ls;
#pragma unroll
        for (int c8 = 0; c8 < 24; ++c8) {
            uint4 v = *reinterpret_cast<const uint4*>(&rp[c8 * 8]);
            const unsigned short* pe = reinterpret_cast<const unsigned short*>(&v);
            unsigned short o8[8];
#pragma unroll
            for (int e = 0; e < 8; ++e) o8[e] = f2bf(bf2f(pe[e]) * inv);
            *reinterpret_cast<uint4*>(&rp[c8 * 8]) = *reinterpret_cast<const uint4*>(o8);
        }
    }
    f32x4 accp[2] = {};
    for (int kc = 0; kc < 24; ++kc) {
        bf16x8 a = *reinterpret_cast<const bf16x8*>(&smS[(wave * 16 + l15) * SP + kc * 32 + quad * 8]);
#pragma unroll
        for (int ct = 0; ct < 2; ++ct) {
            bf16x8 b = *reinterpret_cast<const bf16x8*>(&Vt[(hb + ct * 16 + l15) * 768 + kc * 32 + quad * 8]);
            accp[ct] = __builtin_amdgcn_mfma_f32_16x16x32_bf16(a, b, accp[ct], 0, 0, 0);
        }
    }
#pragma unroll
    for (int ct = 0; ct < 2; ++ct)
#pragma unroll
        for (int r = 0; r < 4; ++r) {
            int row = q0 + wave * 16 + quad * 4 + r;
            Obf[row * 256 + hb + ct * 16 + l15] = f2bf(accp[ct][r]);
        }
}

// ---------------- fused pair MLP (transposed, fp8), 1 i x 64 j -------------
#define S1 296   // bytes: 288 fp8 (256 cross + 32 spatial/pad) + 8 pad
#define S2 136   // bytes: 128 fp8 + 8 pad
#define S3 72    // bytes: 64 fp8 + 8 pad

__global__ __launch_bounds__(256, 4) void pair_mlp(
    const float* __restrict__ att, const unsigned short* __restrict__ attb,
    const float* __restrict__ AB,
    const unsigned char* __restrict__ w1c_f8, const unsigned char* __restrict__ w2g_f8,
    const unsigned char* __restrict__ w3_f8, const unsigned char* __restrict__ w4_f8,
    const float* __restrict__ boxes,
    const float* __restrict__ c1, const float* __restrict__ c2,
    const float* __restrict__ b3, const float* __restrict__ b4,
    const float* __restrict__ w5, const float* __restrict__ b5,
    float* __restrict__ out)
{
    __shared__ __align__(16) unsigned char smH[64 * S1];   // 18.5 KB, reused
    __shared__ float s_psum[64][4], s_pssq[64][4];
    __shared__ float s_mu[64], s_rs[64];
    __shared__ float s_l5[64][2];

    const int i    = blockIdx.x;
    const int j0   = blockIdx.y * 64;
    const int tid  = threadIdx.x;
    const int wave = tid >> 6;
    const int lane = tid & 63;
    const int l15  = lane & 15;
    const int quad = lane >> 4;

    // ---- stage scaledA fp8: rows j, cols 0..255 = att_i.*att_j ----
    {
        const int g = tid & 63;                      // dword group, loop-invariant
        float4 fi4 = *reinterpret_cast<const float4*>(&att[i * 256 + g * 4]);
#pragma unroll
        for (int it = 0; it < 16; ++it) {
            int r = (tid >> 6) + it * 4;
            uint2 aj = *reinterpret_cast<const uint2*>(&attb[(j0 + r) * 256 + g * 4]);
            float a0 = __uint_as_float(aj.x << 16);
            float a1 = __uint_as_float(aj.x & 0xffff0000u);
            float a2 = __uint_as_float(aj.y << 16);
            float a3 = __uint_as_float(aj.y & 0xffff0000u);
            *reinterpret_cast<int*>(&smH[r * S1 + g * 4]) =
                pk4_fp8(a0 * fi4.x, a1 * fi4.y, a2 * fi4.z, a3 * fi4.w);
        }
    }
    // spatial tail cols 256..287: [xd, |yd|, yd, 0...]
    if (tid < 64) {
        int j = j0 + tid;
        float xd = fabsf(boxes[i * 4 + 0] - boxes[j * 4 + 0]);
        float yd = boxes[i * 4 + 1] - boxes[j * 4 + 1];
        *reinterpret_cast<int*>(&smH[tid * S1 + 256]) = pk4_fp8(xd, fabsf(yd), yd, 0.f);
        *reinterpret_cast<int*>(&smH[tid * S1 + 260]) = 0;
        *reinterpret_cast<long long*>(&smH[tid * S1 + 264]) = 0;
        *reinterpret_cast<long long*>(&smH[tid * S1 + 272]) = 0;
        *reinterpret_cast<long long*>(&smH[tid * S1 + 280]) = 0;
    }
    __syncthreads();                                          // B0

    // ======== GEMM1^T (fp8, K=288): D1[o][j], wave owns o-slice of 64 ======
    f32x4 acc1[4][4] = {};
    for (int kc = 0; kc < 9; ++kc) {
        long long a[4];
#pragma unroll
        for (int mt = 0; mt < 4; ++mt)
            a[mt] = *reinterpret_cast<const long long*>(&w1c_f8[((kc * 16 + wave * 4 + mt) * 64 + lane) * 8]);
#pragma unroll
        for (int nt = 0; nt < 4; ++nt) {
            long long b = *reinterpret_cast<const long long*>(&smH[(nt * 16 + l15) * S1 + kc * 32 + quad * 8]);
#pragma unroll
            for (int mt = 0; mt < 4; ++mt)
                acc1[mt][nt] = __builtin_amdgcn_mfma_f32_16x16x32_fp8_fp8(a[mt], b, acc1[mt][nt], 0, 0, 0);
        }
    }

    // ---- epilogue1: + A_i[o] + B_j[o], relu, stats ----
    const int o0 = wave * 64;
    float vsum[4] = {}, vssq[4] = {};
#pragma unroll
    for (int mt = 0; mt < 4; ++mt) {
        int o = o0 + mt * 16 + quad * 4;
        float4 Ai = *reinterpret_cast<const float4*>(&AB[i * 512 + o]);
        float AiA[4] = {Ai.x, Ai.y, Ai.z, Ai.w};
#pragma unroll
        for (int nt = 0; nt < 4; ++nt) {
            int j = nt * 16 + l15;
            float4 Bj = *reinterpret_cast<const float4*>(&AB[(j0 + j) * 512 + 256 + o]);
            float BjA[4] = {Bj.x, Bj.y, Bj.z, Bj.w};
#pragma unroll
            for (int r = 0; r < 4; ++r) {
                float v = fmaxf(acc1[mt][nt][r] + AiA[r] + BjA[r], 0.f);
                acc1[mt][nt][r] = v;
                vsum[nt] += v; vssq[nt] += v * v;
            }
        }
    }
#pragma unroll
    for (int nt = 0; nt < 4; ++nt) {
        vsum[nt] += __shfl_xor(vsum[nt], 16, 64);
        vsum[nt] += __shfl_xor(vsum[nt], 32, 64);
        vssq[nt] += __shfl_xor(vssq[nt], 16, 64);
        vssq[nt] += __shfl_xor(vssq[nt], 32, 64);
    }
    if (quad == 0)
#pragma unroll
        for (int nt = 0; nt < 4; ++nt) {
            s_psum[nt * 16 + l15][wave] = vsum[nt];
            s_pssq[nt * 16 + l15][wave] = vssq[nt];
        }
    __syncthreads();                                          // B1: scaledA reads done
    // h1 fp8 write: [j][o], 4 consecutive o per ds_write_b32
#pragma unroll
    for (int mt = 0; mt < 4; ++mt) {
        int o = o0 + mt * 16 + quad * 4;
#pragma unroll
        for (int nt = 0; nt < 4; ++nt) {
            int j = nt * 16 + l15;
            *reinterpret_cast<int*>(&smH[j * S1 + o]) =
                pk4_fp8(acc1[mt][nt][0], acc1[mt][nt][1], acc1[mt][nt][2], acc1[mt][nt][3]);
        }
    }
    if (wave == 0) {   // finalize LN stats
        int j = lane;
        float sm = (s_psum[j][0] + s_psum[j][1] + s_psum[j][2] + s_psum[j][3]) * (1.0f / 256.0f);
        float sq = (s_pssq[j][0] + s_pssq[j][1] + s_pssq[j][2] + s_pssq[j][3]) * (1.0f / 256.0f);
        s_mu[j] = sm;
        s_rs[j] = rsqrtf(sq - sm * sm + 1e-5f);
    }
    __syncthreads();                                          // B2: h1 + stats ready

    // ======== GEMM2^T (fp8, K=256): D2[p][j] ========
    f32x4 acc2[2][4] = {};
    for (int kc = 0; kc < 8; ++kc) {
        long long a[2];
#pragma unroll
        for (int mt = 0; mt < 2; ++mt)
            a[mt] = *reinterpret_cast<const long long*>(&w2g_f8[((kc * 8 + wave * 2 + mt) * 64 + lane) * 8]);
#pragma unroll
        for (int nt = 0; nt < 4; ++nt) {
            long long b = *reinterpret_cast<const long long*>(&smH[(nt * 16 + l15) * S1 + kc * 32 + quad * 8]);
#pragma unroll
            for (int mt = 0; mt < 2; ++mt)
                acc2[mt][nt] = __builtin_amdgcn_mfma_f32_16x16x32_fp8_fp8(a[mt], b, acc2[mt][nt], 0, 0, 0);
        }
    }
    __syncthreads();                                          // B3: h1 reads done
    // epilogue2: LN-folded affine + relu -> h2 fp8 [j][p]
#pragma unroll
    for (int mt = 0; mt < 2; ++mt) {
        int p = wave * 32 + mt * 16 + quad * 4;
        float4 C1 = *reinterpret_cast<const float4*>(&c1[p]);
        float4 C2 = *reinterpret_cast<const float4*>(&c2[p]);
        float C1A[4] = {C1.x, C1.y, C1.z, C1.w};
        float C2A[4] = {C2.x, C2.y, C2.z, C2.w};
#pragma unroll
        for (int nt = 0; nt < 4; ++nt) {
            int j = nt * 16 + l15;
            float mu = s_mu[j], rs = s_rs[j];
            float vv[4];
#pragma unroll
            for (int r = 0; r < 4; ++r)
                vv[r] = fmaxf(rs * (acc2[mt][nt][r] - mu * C2A[r]) + C1A[r], 0.f);
            *reinterpret_cast<int*>(&smH[j * S2 + p]) = pk4_fp8(vv[0], vv[1], vv[2], vv[3]);
        }
    }
    __syncthreads();                                          // B4: h2 ready

    // ======== GEMM3^T (fp8, K=128): D3[q][j] ========
    f32x4 acc3[4] = {};
    for (int kc = 0; kc < 4; ++kc) {
        long long a = *reinterpret_cast<const long long*>(&w3_f8[((kc * 4 + wave) * 64 + lane) * 8]);
#pragma unroll
        for (int nt = 0; nt < 4; ++nt) {
            long long b = *reinterpret_cast<const long long*>(&smH[(nt * 16 + l15) * S2 + kc * 32 + quad * 8]);
            acc3[nt] = __builtin_amdgcn_mfma_f32_16x16x32_fp8_fp8(a, b, acc3[nt], 0, 0, 0);
        }
    }
    __syncthreads();                                          // B5: h2 reads done
    {
        int q = wave * 16 + quad * 4;
        float4 B3 = *reinterpret_cast<const float4*>(&b3[q]);
        float B3A[4] = {B3.x, B3.y, B3.z, B3.w};
#pragma unroll
        for (int nt = 0; nt < 4; ++nt) {
            int j = nt * 16 + l15;
            float vv[4];
#pragma unroll
            for (int r = 0; r < 4; ++r)
                vv[r] = fmaxf(acc3[nt][r] + B3A[r], 0.f);
            *reinterpret_cast<int*>(&smH[j * S3 + q]) = pk4_fp8(vv[0], vv[1], vv[2], vv[3]);
        }
    }
    __syncthreads();                                          // B6: h3 ready

    // ======== GEMM4^T (fp8, K=64) + head ========
    const int mt4 = wave & 1;        // o4 16-tile
    const int jh  = wave >> 1;       // j 32-half
    f32x4 acc4[2] = {};
#pragma unroll
    for (int kc = 0; kc < 2; ++kc) {
        long long a = *reinterpret_cast<const long long*>(&w4_f8[((kc * 2 + mt4) * 64 + lane) * 8]);
#pragma unroll
        for (int nt = 0; nt < 2; ++nt) {
            int j = jh * 32 + nt * 16 + l15;
            long long b = *reinterpret_cast<const long long*>(&smH[j * S3 + kc * 32 + quad * 8]);
            acc4[nt] = __builtin_amdgcn_mfma_f32_16x16x32_fp8_fp8(a, b, acc4[nt], 0, 0, 0);
        }
    }
    {
        int o4 = mt4 * 16 + quad * 4;
        float4 B4 = *reinterpret_cast<const float4*>(&b4[o4]);
        float4 W5 = *reinterpret_cast<const float4*>(&w5[o4]);
        float B4A[4] = {B4.x, B4.y, B4.z, B4.w};
        float W5A[4] = {W5.x, W5.y, W5.z, W5.w};
#pragma unroll
        for (int nt = 0; nt < 2; ++nt) {
            float part = 0.f;
#pragma unroll
            for (int r = 0; r < 4; ++r)
                part += fmaxf(acc4[nt][r] + B4A[r], 0.f) * W5A[r];
            part += __shfl_xor(part, 16, 64);
            part += __shfl_xor(part, 32, 64);
            if (quad == 0)
                s_l5[jh * 32 + nt * 16 + l15][mt4] = part;
        }
    }
    __syncthreads();                                          // B7
    if (tid < 64) {
        int j = j0 + tid;
        float v = s_l5[tid][0] + s_l5[tid][1] + b5[0];
        out[i * 768 + j] = (j == i) ? -1.0e9f : v;
    }
}

// ---------------------------------------------------------------------------
extern "C" void kernel_launch(void* const* d_in, const int* in_sizes, int n_in,
                              void* d_out, int out_size, void* d_ws, size_t ws_size,
                              hipStream_t stream)
{
    const float* features   = (const float*)d_in[0];
    const float* boxes      = (const float*)d_in[1];
    const float* in_proj_w  = (const float*)d_in[2];
    const float* in_proj_b  = (const float*)d_in[3];
    const float* out_proj_w = (const float*)d_in[4];
    const float* out_proj_b = (const float*)d_in[5];
    const float* w1  = (const float*)d_in[6];
    const float* b1  = (const float*)d_in[7];
    const float* ln_g = (const float*)d_in[8];
    const float* ln_b = (const float*)d_in[9];
    const float* w2  = (const float*)d_in[10];
    const float* b2  = (const float*)d_in[11];
    const float* w3  = (const float*)d_in[12];
    const float* b3  = (const float*)d_in[13];
    const float* w4  = (const float*)d_in[14];
    const float* b4  = (const float*)d_in[15];
    const float* w5  = (const float*)d_in[16];
    const float* b5  = (const float*)d_in[17];
    float* out = (float*)d_out;

    // ---- workspace layout ----
    char* p = (char*)d_ws;
    unsigned short* qkvb  = (unsigned short*)p; p += 768 * 768 * 2;
    unsigned short* Vt    = (unsigned short*)p; p += 256 * 768 * 2;
    unsigned short* Obf   = (unsigned short*)p; p += 768 * 256 * 2;
    unsigned short* attb  = (unsigned short*)p; p += 768 * 256 * 2;
    float* att = (float*)p; p += 768 * 256 * 4;
    float* AB  = (float*)p; p += 768 * 512 * 4;
    unsigned short* featb  = (unsigned short*)p; p += 196608 * 2;
    unsigned short* inWb   = (unsigned short*)p; p += 196608 * 2;
    unsigned short* WcatB  = (unsigned short*)p; p += 196608 * 2;   // [outW;Wcomb]
    unsigned short* outWTb = (unsigned short*)p; p += 65536 * 2;
    unsigned short* wABb   = (unsigned short*)p; p += 131072 * 2;
    unsigned char* w1c_f8  = (unsigned char*)p; p += 73728;
    unsigned char* w2g_f8  = (unsigned char*)p; p += 32768;
    unsigned char* w3_f8   = (unsigned char*)p; p += 8192;
    unsigned char* w4_f8   = (unsigned char*)p; p += 2048;
    float* bias768 = (float*)p; p += 768 * 4;
    float* c1v     = (float*)p; p += 128 * 4;
    float* c2v     = (float*)p; p += 128 * 4;
    float* biasZ   = (float*)p; p += 256 * 4;

    pack_all<<<dim3(3021), dim3(256), 0, stream>>>(features, in_proj_w,
        out_proj_w, w1, w2, w3, w4, b1, ln_g, ln_b, b2, out_proj_b,
        featb, inWb, WcatB, outWTb, wABb, w1c_f8, w2g_f8, w3_f8, w4_f8,
        bias768, c1v, c2v, biasZ);
    // Wcomb = wAB @ outW  -> bf16 rows 256..767 of WcatB
    gemm_bf<<<dim3(8, 4), dim3(256), 0, stream>>>(wABb, outWTb, biasZ,
        (float*)nullptr, WcatB + 65536, (unsigned short*)nullptr, 256, 256, 256, 1 << 30);
    // qkv: Q,K rows -> qkvb; V cols (>=512) transposed -> Vt
    gemm_bf<<<dim3(12, 12), dim3(256), 0, stream>>>(featb, inWb, in_proj_b,
        (float*)nullptr, qkvb, Vt, 768, 256, 768, 512);
    attn_mfma<<<dim3(8, 12), dim3(256), 0, stream>>>(qkvb, Vt, Obf);
    // [att | AB] = O @ WcatB^T + bias768
    gemm_attab<<<dim3(12, 12), dim3(256), 0, stream>>>(Obf, WcatB, bias768,
        att, attb, AB);
    pair_mlp<<<dim3(768, 12), dim3(256), 0, stream>>>(att, attb, AB,
        w1c_f8, w2g_f8, w3_f8, w4_f8, boxes, c1v, c2v,
        b3, b4, w5, b5, out);
}

// Round 7
// 303.320 us; speedup vs baseline: 1.2466x; 1.0045x over previous
//
#include <hip/hip_runtime.h>

// ---------------------------------------------------------------------------
// ImprovedLinkingPredictor round 7.
// - GEMM1/GEMM2 of pair MLP on 32x32x16 fp8 MFMA (half the issue slots of
//   16x16x32); GEMM3/4 stay 16x16. LDS layouts are plain row-major [j][feat]
//   so shapes mix freely.
// - h2/h3 in separate LDS regions: 6 barriers instead of 8.
// - attn_mfma: 32-row q-tiles (192 blocks, 2x parallelism).
// ---------------------------------------------------------------------------

typedef __attribute__((ext_vector_type(8))) __bf16 bf16x8;    // bf16 MFMA frag
typedef __attribute__((ext_vector_type(4))) float f32x4;      // 16x16 C/D
typedef __attribute__((ext_vector_type(16))) float f32x16;    // 32x32 C/D

__device__ __forceinline__ float bf2f(unsigned short u) {
    return __uint_as_float(((unsigned int)u) << 16);
}
__device__ __forceinline__ unsigned short f2bf(float f) {
    union { __bf16 b; unsigned short u; } cv;
    cv.b = (__bf16)f;
    return cv.u;
}
__device__ __forceinline__ int pk4_fp8(float a, float b, float c, float d) {
    int w = __builtin_amdgcn_cvt_pk_fp8_f32(a, b, 0, false);
    w = __builtin_amdgcn_cvt_pk_fp8_f32(c, d, w, true);
    return w;
}
__device__ __forceinline__ unsigned char f2fp8(float v) {
    return (unsigned char)(__builtin_amdgcn_cvt_pk_fp8_f32(v, 0.f, 0, false) & 0xff);
}

// ---------------- pack: bf16/fp8 casts + fragment-major weight tables -------
// 16x16 fp8 frag-major: (o,k) at ((kc*NT + o>>4)*64 + lane)*8 + e,
//   lane=(o&15)|(((k>>3)&3)<<4), e=k&7, kc=k>>5.
// 32x32 fp8 frag-major: (o,k) at ((k16*NT + o>>5)*64 + lane)*8 + e,
//   lane=(o&31)|(((k>>3)&1)<<5), e=k&7, k16=k>>4.
__global__ __launch_bounds__(256) void pack_all(
    const float* __restrict__ features, const float* __restrict__ in_proj_w,
    const float* __restrict__ out_proj_w, const float* __restrict__ w1,
    const float* __restrict__ w2, const float* __restrict__ w3,
    const float* __restrict__ w4, const float* __restrict__ b1,
    const float* __restrict__ ln_g, const float* __restrict__ ln_b,
    const float* __restrict__ b2, const float* __restrict__ out_proj_b,
    unsigned short* __restrict__ featb, unsigned short* __restrict__ inWb,
    unsigned short* __restrict__ WcatB, unsigned short* __restrict__ outWTb,
    unsigned short* __restrict__ wABb,
    unsigned char* __restrict__ w1c_f8, unsigned char* __restrict__ w2g_f8,
    unsigned char* __restrict__ w3_f8, unsigned char* __restrict__ w4_f8,
    float* __restrict__ bias768, float* __restrict__ c1, float* __restrict__ c2,
    float* __restrict__ biasZ)
{
    int t = blockIdx.x * 256 + threadIdx.x;
    if (t < 196608) {                                   // featb
        featb[t] = f2bf(features[t]);
    } else if (t < 393216) {                            // inWb
        int u = t - 196608; inWb[u] = f2bf(in_proj_w[u]);
    } else if (t < 458752) {                            // WcatB rows 0..255 = outW
        int u = t - 393216; WcatB[u] = f2bf(out_proj_w[u]);
    } else if (t < 524288) {                            // outWTb = outW^T
        int u = t - 458752; int e = u >> 8, d = u & 255;
        outWTb[u] = f2bf(out_proj_w[d * 256 + e]);
    } else if (t < 655360) {                            // wABb = [w1a ; w1b]
        int u = t - 524288; int n = u >> 8, k = u & 255;
        float v = (n < 256) ? w1[n * 771 + k] : w1[(n - 256) * 771 + 256 + k];
        wABb[u] = f2bf(v);
    } else if (t < 729088) {                            // w1c_f8 32x32 frag, K=288,N=256
        int u = t - 655360;
        int e = u & 7, lane = (u >> 3) & 63, f = u >> 9;
        int ot = f & 7, k16 = f >> 3;                   // ot 0..7, k16 0..17
        int o = ot * 32 + (lane & 31);
        int k = k16 * 16 + ((lane >> 5) & 1) * 8 + e;
        float v;
        if (k < 256)            v = w1[o * 771 + 512 + k];
        else if (k < 259)       v = w1[o * 771 + 768 + (k - 256)];
        else                    v = 0.f;
        w1c_f8[u] = f2fp8(v);
    } else if (t < 761856) {                            // w2g_f8 32x32 frag, K=256,N=128
        int u = t - 729088;
        int e = u & 7, lane = (u >> 3) & 63, f = u >> 9;
        int pt = f & 3, k16 = f >> 2;                   // pt 0..3, k16 0..15
        int p = pt * 32 + (lane & 31);
        int k = k16 * 16 + ((lane >> 5) & 1) * 8 + e;
        w2g_f8[u] = f2fp8(w2[p * 256 + k] * ln_g[k]);
    } else if (t < 770048) {                            // w3_f8 16x16 frag, K=128,N=64
        int u = t - 761856;
        int e = u & 7, lane = (u >> 3) & 63, f = u >> 9;
        int l15 = lane & 15, quad = lane >> 4;
        int mt = f & 3, kc = f >> 2;
        int o = mt * 16 + l15, k = kc * 32 + quad * 8 + e;
        w3_f8[u] = f2fp8(w3[o * 128 + k]);
    } else if (t < 772096) {                            // w4_f8 16x16 frag, K=64,N=32
        int u = t - 770048;
        int e = u & 7, lane = (u >> 3) & 63, f = u >> 9;
        int l15 = lane & 15, quad = lane >> 4;
        int mt = f & 1, kc = f >> 1;
        int o = mt * 16 + l15, k = kc * 32 + quad * 8 + e;
        w4_f8[u] = f2fp8(w4[o * 64 + k]);
    } else if (t < 772864) {                            // bias768
        int n = t - 772096;
        if (n < 256) bias768[n] = out_proj_b[n];
        else {
            int m = n - 256;
            float s = 0.f;
            for (int d = 0; d < 256; d += 4) {
                float4 ob = *reinterpret_cast<const float4*>(&out_proj_b[d]);
                const float* wr = (m < 256) ? &w1[m * 771 + d]
                                            : &w1[(m - 256) * 771 + 256 + d];
                float4 w = *reinterpret_cast<const float4*>(wr);
                s += ob.x * w.x + ob.y * w.y + ob.z * w.z + ob.w * w.w;
            }
            bias768[n] = s + ((m < 256) ? b1[m] : 0.f);
        }
    } else if (t < 772992) {                            // c1/c2 LN-fold constants
        int p = t - 772864;
        float s2 = 0.f, s1 = 0.f;
        for (int k = 0; k < 256; k += 4) {
            float4 w = *reinterpret_cast<const float4*>(&w2[p * 256 + k]);
            float4 g = *reinterpret_cast<const float4*>(&ln_g[k]);
            float4 lb = *reinterpret_cast<const float4*>(&ln_b[k]);
            s2 += g.x * w.x + g.y * w.y + g.z * w.z + g.w * w.w;
            s1 += lb.x * w.x + lb.y * w.y + lb.z * w.z + lb.w * w.w;
        }
        c2[p] = s2;
        c1[p] = s1 + b2[p];
    } else if (t < 773248) {                            // biasZ = zeros
        biasZ[t - 772992] = 0.f;
    }
}

// ---------------- bf16 MFMA GEMM: C[M,N] = A[M,K] @ W[N,K]^T + bias --------
__global__ __launch_bounds__(256) void gemm_bf(
    const unsigned short* __restrict__ A, const unsigned short* __restrict__ W,
    const float* __restrict__ bias, float* __restrict__ Cf,
    unsigned short* __restrict__ Cbf, unsigned short* __restrict__ Vt,
    int N, int K, int ldc, int tcol0)
{
    const int wv = threadIdx.x >> 6, lane = threadIdx.x & 63;
    const int l15 = lane & 15, quad = lane >> 4;
    const int row0 = blockIdx.x * 64 + wv * 16;
    const int col0 = blockIdx.y * 64;
    f32x4 acc[4] = {};
    for (int kc = 0; kc < (K >> 5); ++kc) {
        bf16x8 a = *reinterpret_cast<const bf16x8*>(&A[(row0 + l15) * K + kc * 32 + quad * 8]);
#pragma unroll
        for (int ct = 0; ct < 4; ++ct) {
            bf16x8 b = *reinterpret_cast<const bf16x8*>(&W[(col0 + ct * 16 + l15) * K + kc * 32 + quad * 8]);
            acc[ct] = __builtin_amdgcn_mfma_f32_16x16x32_bf16(a, b, acc[ct], 0, 0, 0);
        }
    }
#pragma unroll
    for (int ct = 0; ct < 4; ++ct)
#pragma unroll
        for (int r = 0; r < 4; ++r) {
            int row = row0 + quad * 4 + r, col = col0 + ct * 16 + l15;
            float v = acc[ct][r] + bias[col];
            if (Vt && col >= tcol0) {
                Vt[(col - tcol0) * 768 + row] = f2bf(v);
            } else {
                if (Cf)  Cf[row * ldc + col] = v;
                if (Cbf) Cbf[row * ldc + col] = f2bf(v);
            }
        }
}

// ---------------- fused [att | AB] GEMM ------------------------------------
__global__ __launch_bounds__(256) void gemm_attab(
    const unsigned short* __restrict__ A, const unsigned short* __restrict__ W,
    const float* __restrict__ bias, float* __restrict__ att,
    unsigned short* __restrict__ attb, float* __restrict__ AB)
{
    const int wv = threadIdx.x >> 6, lane = threadIdx.x & 63;
    const int l15 = lane & 15, quad = lane >> 4;
    const int row0 = blockIdx.x * 64 + wv * 16;
    const int col0 = blockIdx.y * 64;
    f32x4 acc[4] = {};
    for (int kc = 0; kc < 8; ++kc) {
        bf16x8 a = *reinterpret_cast<const bf16x8*>(&A[(row0 + l15) * 256 + kc * 32 + quad * 8]);
#pragma unroll
        for (int ct = 0; ct < 4; ++ct) {
            bf16x8 b = *reinterpret_cast<const bf16x8*>(&W[(col0 + ct * 16 + l15) * 256 + kc * 32 + quad * 8]);
            acc[ct] = __builtin_amdgcn_mfma_f32_16x16x32_bf16(a, b, acc[ct], 0, 0, 0);
        }
    }
#pragma unroll
    for (int ct = 0; ct < 4; ++ct)
#pragma unroll
        for (int r = 0; r < 4; ++r) {
            int row = row0 + quad * 4 + r, col = col0 + ct * 16 + l15;
            float v = acc[ct][r] + bias[col];
            if (col < 256) {
                att[row * 256 + col] = v;
                attb[row * 256 + col] = f2bf(v);
            } else {
                AB[row * 512 + (col - 256)] = v;
            }
        }
}

// ---------------- fused MFMA attention: 32-row q-tiles ---------------------
#define SP 776

__global__ __launch_bounds__(256) void attn_mfma(
    const unsigned short* __restrict__ qkvb, const unsigned short* __restrict__ Vt,
    unsigned short* __restrict__ Obf)
{
    __shared__ __align__(16) unsigned short smS[32 * SP];   // 49.7 KB
    const int h = blockIdx.x, q0 = blockIdx.y * 32, hb = h * 32;
    const int tid = threadIdx.x, wave = tid >> 6, lane = tid & 63;
    const int l15 = lane & 15, quad = lane >> 4;

    // ---- QK^T: wave covers cols [wave*192, +192) x 32 rows ----
    bf16x8 af[2];
#pragma unroll
    for (int mt = 0; mt < 2; ++mt)
        af[mt] = *reinterpret_cast<const bf16x8*>(&qkvb[(q0 + mt * 16 + l15) * 768 + hb + quad * 8]);
#pragma unroll
    for (int ct = 0; ct < 12; ++ct) {
        int n0 = wave * 192 + ct * 16;
        bf16x8 b = *reinterpret_cast<const bf16x8*>(&qkvb[(n0 + l15) * 768 + 256 + hb + quad * 8]);
#pragma unroll
        for (int mt = 0; mt < 2; ++mt) {
            f32x4 c = {};
            c = __builtin_amdgcn_mfma_f32_16x16x32_bf16(af[mt], b, c, 0, 0, 0);
#pragma unroll
            for (int r = 0; r < 4; ++r)
                smS[(mt * 16 + quad * 4 + r) * SP + n0 + l15] =
                    f2bf(c[r] * 0.17677669529663689f);
        }
    }
    __syncthreads();

    {   // row softmax: 8 threads per row, 96 cols each
        const int row = tid >> 3, part = tid & 7;
        unsigned short* rp = &smS[row * SP + part * 96];
        float mx = -3.0e38f;
#pragma unroll
        for (int c8 = 0; c8 < 12; ++c8) {
            uint4 v = *reinterpret_cast<const uint4*>(&rp[c8 * 8]);
            const unsigned short* pe = reinterpret_cast<const unsigned short*>(&v);
#pragma unroll
            for (int e = 0; e < 8; ++e) mx = fmaxf(mx, bf2f(pe[e]));
        }
        mx = fmaxf(mx, __shfl_xor(mx, 1, 64));
        mx = fmaxf(mx, __shfl_xor(mx, 2, 64));
        mx = fmaxf(mx, __shfl_xor(mx, 4, 64));
        float ls = 0.f;
#pragma unroll
        for (int c8 = 0; c8 < 12; ++c8) {
            uint4 v = *reinterpret_cast<const uint4*>(&rp[c8 * 8]);
            const unsigned short* pe = reinterpret_cast<const unsigned short*>(&v);
            unsigned short o8[8];
#pragma unroll
            for (int e = 0; e < 8; ++e) {
                float ev = __expf(bf2f(pe[e]) - mx);
                ls += ev;
                o8[e] = f2bf(ev);
            }
            *reinterpret_cast<uint4*>(&rp[c8 * 8]) = *reinterpret_cast<const uint4*>(o8);
        }
        ls += __shfl_xor(ls, 1, 64);
        ls += __shfl_xor(ls, 2, 64);
        ls += __shfl_xor(ls, 4, 64);
        float inv = 1.0f / ls;
#pragma unroll
        for (int c8 = 0; c8 < 12; ++c8) {
            uint4 v = *reinterpret_cast<const uint4*>(&rp[c8 * 8]);
            const unsigned short* pe = reinterpret_cast<const unsigned short*>(&v);
            unsigned short o8[8];
#pragma unroll
            for (int e = 0; e < 8; ++e) o8[e] = f2bf(bf2f(pe[e]) * inv);
            *reinterpret_cast<uint4*>(&rp[c8 * 8]) = *reinterpret_cast<const uint4*>(o8);
        }
    }
    __syncthreads();   // softmax rows span waves -> full barrier before PV

    // ---- PV: wave pair covers 16 rows; wave&1 selects 16-col group --------
    const int row0 = (wave >> 1) * 16, cg = wave & 1;
    f32x4 accp = {};
    for (int kc = 0; kc < 24; ++kc) {
        bf16x8 a = *reinterpret_cast<const bf16x8*>(&smS[(row0 + l15) * SP + kc * 32 + quad * 8]);
        bf16x8 b = *reinterpret_cast<const bf16x8*>(&Vt[(hb + cg * 16 + l15) * 768 + kc * 32 + quad * 8]);
        accp = __builtin_amdgcn_mfma_f32_16x16x32_bf16(a, b, accp, 0, 0, 0);
    }
#pragma unroll
    for (int r = 0; r < 4; ++r) {
        int row = q0 + row0 + quad * 4 + r;
        Obf[row * 256 + hb + cg * 16 + l15] = f2bf(accp[r]);
    }
}

// ---------------- fused pair MLP (transposed, fp8, 32x32 heads) ------------
#define S1 296   // scaledA/h1 row stride (288 fp8 + 8 pad)
#define S2 136   // h2 row stride
#define S3 72    // h3 row stride

__global__ __launch_bounds__(256, 4) void pair_mlp(
    const float* __restrict__ att, const unsigned short* __restrict__ attb,
    const float* __restrict__ AB,
    const unsigned char* __restrict__ w1c_f8, const unsigned char* __restrict__ w2g_f8,
    const unsigned char* __restrict__ w3_f8, const unsigned char* __restrict__ w4_f8,
    const float* __restrict__ boxes,
    const float* __restrict__ c1, const float* __restrict__ c2,
    const float* __restrict__ b3, const float* __restrict__ b4,
    const float* __restrict__ w5, const float* __restrict__ b5,
    float* __restrict__ out)
{
    __shared__ __align__(16) unsigned char smH[64 * S1];    // scaledA -> h1
    __shared__ __align__(16) unsigned char smH2[64 * S2];   // h2
    __shared__ __align__(16) unsigned char smH3[64 * S3];   // h3
    __shared__ float s_psum[64][4], s_pssq[64][4];
    __shared__ float s_mu[64], s_rs[64];
    __shared__ float s_l5[64][2];

    const int i    = blockIdx.x;
    const int j0   = blockIdx.y * 64;
    const int tid  = threadIdx.x;
    const int wave = tid >> 6;
    const int lane = tid & 63;
    const int l15  = lane & 15;
    const int quad = lane >> 4;
    const int l31  = lane & 31;
    const int half = lane >> 5;

    // ---- stage scaledA fp8: rows j, cols 0..255 = att_i.*att_j ----
    {
        const int g = tid & 63;
        float4 fi4 = *reinterpret_cast<const float4*>(&att[i * 256 + g * 4]);
#pragma unroll
        for (int it = 0; it < 16; ++it) {
            int r = (tid >> 6) + it * 4;
            uint2 aj = *reinterpret_cast<const uint2*>(&attb[(j0 + r) * 256 + g * 4]);
            float a0 = __uint_as_float(aj.x << 16);
            float a1 = __uint_as_float(aj.x & 0xffff0000u);
            float a2 = __uint_as_float(aj.y << 16);
            float a3 = __uint_as_float(aj.y & 0xffff0000u);
            *reinterpret_cast<int*>(&smH[r * S1 + g * 4]) =
                pk4_fp8(a0 * fi4.x, a1 * fi4.y, a2 * fi4.z, a3 * fi4.w);
        }
    }
    if (tid < 64) {   // spatial tail cols 256..287
        int j = j0 + tid;
        float xd = fabsf(boxes[i * 4 + 0] - boxes[j * 4 + 0]);
        float yd = boxes[i * 4 + 1] - boxes[j * 4 + 1];
        *reinterpret_cast<int*>(&smH[tid * S1 + 256]) = pk4_fp8(xd, fabsf(yd), yd, 0.f);
        *reinterpret_cast<int*>(&smH[tid * S1 + 260]) = 0;
        *reinterpret_cast<long long*>(&smH[tid * S1 + 264]) = 0;
        *reinterpret_cast<long long*>(&smH[tid * S1 + 272]) = 0;
        *reinterpret_cast<long long*>(&smH[tid * S1 + 280]) = 0;
    }
    __syncthreads();                                          // B0

    // ======== GEMM1 (32x32x16 fp8, K=288): wave owns o-slice 64 ========
    // C/D: col(j)=lane&31, row(o offset)=(reg&3)+8*(reg>>2)+4*half
    f32x16 acc1[2][2] = {};   // [ot][jt]
    for (int k16 = 0; k16 < 18; ++k16) {
        long long a0 = *reinterpret_cast<const long long*>(&w1c_f8[((k16 * 8 + wave * 2 + 0) * 64 + lane) * 8]);
        long long a1 = *reinterpret_cast<const long long*>(&w1c_f8[((k16 * 8 + wave * 2 + 1) * 64 + lane) * 8]);
#pragma unroll
        for (int jt = 0; jt < 2; ++jt) {
            long long b = *reinterpret_cast<const long long*>(&smH[(jt * 32 + l31) * S1 + k16 * 16 + half * 8]);
            acc1[0][jt] = __builtin_amdgcn_mfma_f32_32x32x16_fp8_fp8(a0, b, acc1[0][jt], 0, 0, 0);
            acc1[1][jt] = __builtin_amdgcn_mfma_f32_32x32x16_fp8_fp8(a1, b, acc1[1][jt], 0, 0, 0);
        }
    }

    // ---- epilogue1: + A_i[o] + B_j[o], relu, stats (j fixed per thread) ----
    const int o0 = wave * 64;
    float vsum[2] = {}, vssq[2] = {};
#pragma unroll
    for (int ot = 0; ot < 2; ++ot)
#pragma unroll
        for (int q4 = 0; q4 < 4; ++q4) {
            int ob = o0 + ot * 32 + q4 * 8 + half * 4;
            float4 Ai = *reinterpret_cast<const float4*>(&AB[i * 512 + ob]);
            float AiA[4] = {Ai.x, Ai.y, Ai.z, Ai.w};
#pragma unroll
            for (int jt = 0; jt < 2; ++jt) {
                int j = jt * 32 + l31;
                float4 Bj = *reinterpret_cast<const float4*>(&AB[(j0 + j) * 512 + 256 + ob]);
                float BjA[4] = {Bj.x, Bj.y, Bj.z, Bj.w};
#pragma unroll
                for (int r = 0; r < 4; ++r) {
                    float v = fmaxf(acc1[ot][jt][q4 * 4 + r] + AiA[r] + BjA[r], 0.f);
                    acc1[ot][jt][q4 * 4 + r] = v;
                    vsum[jt] += v; vssq[jt] += v * v;
                }
            }
        }
#pragma unroll
    for (int jt = 0; jt < 2; ++jt) {
        vsum[jt] += __shfl_xor(vsum[jt], 32, 64);
        vssq[jt] += __shfl_xor(vssq[jt], 32, 64);
    }
    if (half == 0)
#pragma unroll
        for (int jt = 0; jt < 2; ++jt) {
            s_psum[jt * 32 + l31][wave] = vsum[jt];
            s_pssq[jt * 32 + l31][wave] = vssq[jt];
        }
    __syncthreads();                                          // B1: GEMM1 reads done
    // h1 fp8 write into smH (overwrites scaledA region; WAR cleared by B1)
#pragma unroll
    for (int ot = 0; ot < 2; ++ot)
#pragma unroll
        for (int q4 = 0; q4 < 4; ++q4) {
            int ob = o0 + ot * 32 + q4 * 8 + half * 4;
#pragma unroll
            for (int jt = 0; jt < 2; ++jt) {
                int j = jt * 32 + l31;
                *reinterpret_cast<int*>(&smH[j * S1 + ob]) =
                    pk4_fp8(acc1[ot][jt][q4 * 4 + 0], acc1[ot][jt][q4 * 4 + 1],
                            acc1[ot][jt][q4 * 4 + 2], acc1[ot][jt][q4 * 4 + 3]);
            }
        }
    if (wave == 0) {   // finalize LN stats
        int j = lane;
        float sm = (s_psum[j][0] + s_psum[j][1] + s_psum[j][2] + s_psum[j][3]) * (1.0f / 256.0f);
        float sq = (s_pssq[j][0] + s_pssq[j][1] + s_pssq[j][2] + s_pssq[j][3]) * (1.0f / 256.0f);
        s_mu[j] = sm;
        s_rs[j] = rsqrtf(sq - sm * sm + 1e-5f);
    }
    __syncthreads();                                          // B2: h1 + stats ready

    // ======== GEMM2 (32x32x16 fp8, K=256): wave owns p-slice 32 ========
    f32x16 acc2[2] = {};
    for (int k16 = 0; k16 < 16; ++k16) {
        long long a = *reinterpret_cast<const long long*>(&w2g_f8[((k16 * 4 + wave) * 64 + lane) * 8]);
#pragma unroll
        for (int jt = 0; jt < 2; ++jt) {
            long long b = *reinterpret_cast<const long long*>(&smH[(jt * 32 + l31) * S1 + k16 * 16 + half * 8]);
            acc2[jt] = __builtin_amdgcn_mfma_f32_32x32x16_fp8_fp8(a, b, acc2[jt], 0, 0, 0);
        }
    }
    // epilogue2: LN-folded affine + relu -> h2 (separate region, no barrier)
#pragma unroll
    for (int q4 = 0; q4 < 4; ++q4) {
        int pb = wave * 32 + q4 * 8 + half * 4;
        float4 C1 = *reinterpret_cast<const float4*>(&c1[pb]);
        float4 C2 = *reinterpret_cast<const float4*>(&c2[pb]);
        float C1A[4] = {C1.x, C1.y, C1.z, C1.w};
        float C2A[4] = {C2.x, C2.y, C2.z, C2.w};
#pragma unroll
        for (int jt = 0; jt < 2; ++jt) {
            int j = jt * 32 + l31;
            float mu = s_mu[j], rs = s_rs[j];
            float vv[4];
#pragma unroll
            for (int r = 0; r < 4; ++r)
                vv[r] = fmaxf(rs * (acc2[jt][q4 * 4 + r] - mu * C2A[r]) + C1A[r], 0.f);
            *reinterpret_cast<int*>(&smH2[j * S2 + pb]) = pk4_fp8(vv[0], vv[1], vv[2], vv[3]);
        }
    }
    __syncthreads();                                          // B3: h2 ready

    // ======== GEMM3 (16x16x32 fp8, K=128): D3[q][j] ========
    f32x4 acc3[4] = {};
    for (int kc = 0; kc < 4; ++kc) {
        long long a = *reinterpret_cast<const long long*>(&w3_f8[((kc * 4 + wave) * 64 + lane) * 8]);
#pragma unroll
        for (int nt = 0; nt < 4; ++nt) {
            long long b = *reinterpret_cast<const long long*>(&smH2[(nt * 16 + l15) * S2 + kc * 32 + quad * 8]);
            acc3[nt] = __builtin_amdgcn_mfma_f32_16x16x32_fp8_fp8(a, b, acc3[nt], 0, 0, 0);
        }
    }
    {   // epilogue3 -> h3 (separate region, no barrier needed before write)
        int q = wave * 16 + quad * 4;
        float4 B3 = *reinterpret_cast<const float4*>(&b3[q]);
        float B3A[4] = {B3.x, B3.y, B3.z, B3.w};
#pragma unroll
        for (int nt = 0; nt < 4; ++nt) {
            int j = nt * 16 + l15;
            float vv[4];
#pragma unroll
            for (int r = 0; r < 4; ++r)
                vv[r] = fmaxf(acc3[nt][r] + B3A[r], 0.f);
            *reinterpret_cast<int*>(&smH3[j * S3 + q]) = pk4_fp8(vv[0], vv[1], vv[2], vv[3]);
        }
    }
    __syncthreads();                                          // B4: h3 ready

    // ======== GEMM4 (16x16x32 fp8, K=64) + head ========
    const int mt4 = wave & 1;
    const int jh  = wave >> 1;
    f32x4 acc4[2] = {};
#pragma unroll
    for (int kc = 0; kc < 2; ++kc) {
        long long a = *reinterpret_cast<const long long*>(&w4_f8[((kc * 2 + mt4) * 64 + lane) * 8]);
#pragma unroll
        for (int nt = 0; nt < 2; ++nt) {
            int j = jh * 32 + nt * 16 + l15;
            long long b = *reinterpret_cast<const long long*>(&smH3[j * S3 + kc * 32 + quad * 8]);
            acc4[nt] = __builtin_amdgcn_mfma_f32_16x16x32_fp8_fp8(a, b, acc4[nt], 0, 0, 0);
        }
    }
    {
        int o4 = mt4 * 16 + quad * 4;
        float4 B4 = *reinterpret_cast<const float4*>(&b4[o4]);
        float4 W5 = *reinterpret_cast<const float4*>(&w5[o4]);
        float B4A[4] = {B4.x, B4.y, B4.z, B4.w};
        float W5A[4] = {W5.x, W5.y, W5.z, W5.w};
#pragma unroll
        for (int nt = 0; nt < 2; ++nt) {
            float part = 0.f;
#pragma unroll
            for (int r = 0; r < 4; ++r)
                part += fmaxf(acc4[nt][r] + B4A[r], 0.f) * W5A[r];
            part += __shfl_xor(part, 16, 64);
            part += __shfl_xor(part, 32, 64);
            if (quad == 0)
                s_l5[jh * 32 + nt * 16 + l15][mt4] = part;
        }
    }
    __syncthreads();                                          // B5
    if (tid < 64) {
        int j = j0 + tid;
        float v = s_l5[tid][0] + s_l5[tid][1] + b5[0];
        out[i * 768 + j] = (j == i) ? -1.0e9f : v;
    }
}

// ---------------------------------------------------------------------------
extern "C" void kernel_launch(void* const* d_in, const int* in_sizes, int n_in,
                              void* d_out, int out_size, void* d_ws, size_t ws_size,
                              hipStream_t stream)
{
    const float* features   = (const float*)d_in[0];
    const float* boxes      = (const float*)d_in[1];
    const float* in_proj_w  = (const float*)d_in[2];
    const float* in_proj_b  = (const float*)d_in[3];
    const float* out_proj_w = (const float*)d_in[4];
    const float* out_proj_b = (const float*)d_in[5];
    const float* w1  = (const float*)d_in[6];
    const float* b1  = (const float*)d_in[7];
    const float* ln_g = (const float*)d_in[8];
    const float* ln_b = (const float*)d_in[9];
    const float* w2  = (const float*)d_in[10];
    const float* b2  = (const float*)d_in[11];
    const float* w3  = (const float*)d_in[12];
    const float* b3  = (const float*)d_in[13];
    const float* w4  = (const float*)d_in[14];
    const float* b4  = (const float*)d_in[15];
    const float* w5  = (const float*)d_in[16];
    const float* b5  = (const float*)d_in[17];
    float* out = (float*)d_out;

    // ---- workspace layout ----
    char* p = (char*)d_ws;
    unsigned short* qkvb  = (unsigned short*)p; p += 768 * 768 * 2;
    unsigned short* Vt    = (unsigned short*)p; p += 256 * 768 * 2;
    unsigned short* Obf   = (unsigned short*)p; p += 768 * 256 * 2;
    unsigned short* attb  = (unsigned short*)p; p += 768 * 256 * 2;
    float* att = (float*)p; p += 768 * 256 * 4;
    float* AB  = (float*)p; p += 768 * 512 * 4;
    unsigned short* featb  = (unsigned short*)p; p += 196608 * 2;
    unsigned short* inWb   = (unsigned short*)p; p += 196608 * 2;
    unsigned short* WcatB  = (unsigned short*)p; p += 196608 * 2;   // [outW;Wcomb]
    unsigned short* outWTb = (unsigned short*)p; p += 65536 * 2;
    unsigned short* wABb   = (unsigned short*)p; p += 131072 * 2;
    unsigned char* w1c_f8  = (unsigned char*)p; p += 73728;
    unsigned char* w2g_f8  = (unsigned char*)p; p += 32768;
    unsigned char* w3_f8   = (unsigned char*)p; p += 8192;
    unsigned char* w4_f8   = (unsigned char*)p; p += 2048;
    float* bias768 = (float*)p; p += 768 * 4;
    float* c1v     = (float*)p; p += 128 * 4;
    float* c2v     = (float*)p; p += 128 * 4;
    float* biasZ   = (float*)p; p += 256 * 4;

    pack_all<<<dim3(3021), dim3(256), 0, stream>>>(features, in_proj_w,
        out_proj_w, w1, w2, w3, w4, b1, ln_g, ln_b, b2, out_proj_b,
        featb, inWb, WcatB, outWTb, wABb, w1c_f8, w2g_f8, w3_f8, w4_f8,
        bias768, c1v, c2v, biasZ);
    // Wcomb = wAB @ outW -> bf16 rows 256..767 of WcatB
    gemm_bf<<<dim3(8, 4), dim3(256), 0, stream>>>(wABb, outWTb, biasZ,
        (float*)nullptr, WcatB + 65536, (unsigned short*)nullptr, 256, 256, 256, 1 << 30);
    // qkv: Q,K rows -> qkvb; V cols (>=512) transposed -> Vt
    gemm_bf<<<dim3(12, 12), dim3(256), 0, stream>>>(featb, inWb, in_proj_b,
        (float*)nullptr, qkvb, Vt, 768, 256, 768, 512);
    attn_mfma<<<dim3(8, 24), dim3(256), 0, stream>>>(qkvb, Vt, Obf);
    // [att | AB] = O @ WcatB^T + bias768
    gemm_attab<<<dim3(12, 12), dim3(256), 0, stream>>>(Obf, WcatB, bias768,
        att, attb, AB);
    pair_mlp<<<dim3(768, 12), dim3(256), 0, stream>>>(att, attb, AB,
        w1c_f8, w2g_f8, w3_f8, w4_f8, boxes, c1v, c2v,
        b3, b4, w5, b5, out);
}

// Round 8
// 301.168 us; speedup vs baseline: 1.2555x; 1.0071x over previous
//
#include <hip/hip_runtime.h>

// ---------------------------------------------------------------------------
// ImprovedLinkingPredictor round 8.
// - pair_mlp: 16x16 fp8 GEMMs (r6 geometry) + separate h2/h3 LDS regions
//   (6 barriers) + f32 staging loads (no bf16 unpack).
// - Front-end: 4 launches. pack_all absorbs Wcomb (scalar GEMM from raw fp32)
//   and the qkv GEMM (inline f32->bf16 cvt); featb/inWb/wABb packing deleted.
// ---------------------------------------------------------------------------

typedef __attribute__((ext_vector_type(8))) __bf16 bf16x8;    // bf16 MFMA frag
typedef __attribute__((ext_vector_type(4))) float f32x4;      // 16x16 C/D

__device__ __forceinline__ float bf2f(unsigned short u) {
    return __uint_as_float(((unsigned int)u) << 16);
}
__device__ __forceinline__ unsigned short f2bf(float f) {
    union { __bf16 b; unsigned short u; } cv;
    cv.b = (__bf16)f;
    return cv.u;
}
__device__ __forceinline__ unsigned pk2(float lo, float hi) {
    return (unsigned)f2bf(lo) | ((unsigned)f2bf(hi) << 16);
}
__device__ __forceinline__ int pk4_fp8(float a, float b, float c, float d) {
    int w = __builtin_amdgcn_cvt_pk_fp8_f32(a, b, 0, false);
    w = __builtin_amdgcn_cvt_pk_fp8_f32(c, d, w, true);
    return w;
}
__device__ __forceinline__ unsigned char f2fp8(float v) {
    return (unsigned char)(__builtin_amdgcn_cvt_pk_fp8_f32(v, 0.f, 0, false) & 0xff);
}
__device__ __forceinline__ bf16x8 load8f_bf(const float* p) {
    float4 a = *reinterpret_cast<const float4*>(p);
    float4 b = *reinterpret_cast<const float4*>(p + 4);
    union { bf16x8 v; unsigned u[4]; } cv;
    cv.u[0] = pk2(a.x, a.y); cv.u[1] = pk2(a.z, a.w);
    cv.u[2] = pk2(b.x, b.y); cv.u[3] = pk2(b.z, b.w);
    return cv.v;
}

// ---------------- pack_all: packing + Wcomb + qkv GEMM ---------------------
// Elementwise region: 716 blocks. Wcomb region: 512 blocks. qkv: 144 blocks.
// fp8 16x16 frag-major: (o,k) at ((kc*NT + o>>4)*64 + lane)*8 + e,
//   lane=(o&15)|(((k>>3)&3)<<4), e=k&7, kc=k>>5.
__global__ __launch_bounds__(256) void pack_all(
    const float* __restrict__ features, const float* __restrict__ in_proj_w,
    const float* __restrict__ in_proj_b, const float* __restrict__ out_proj_w,
    const float* __restrict__ w1, const float* __restrict__ w2,
    const float* __restrict__ w3, const float* __restrict__ w4,
    const float* __restrict__ b1, const float* __restrict__ ln_g,
    const float* __restrict__ ln_b, const float* __restrict__ b2,
    const float* __restrict__ out_proj_b,
    unsigned short* __restrict__ qkvb, unsigned short* __restrict__ Vt,
    unsigned short* __restrict__ WcatB,
    unsigned char* __restrict__ w1c_f8, unsigned char* __restrict__ w2g_f8,
    unsigned char* __restrict__ w3_f8, unsigned char* __restrict__ w4_f8,
    float* __restrict__ bias768, float* __restrict__ c1, float* __restrict__ c2)
{
    const int blk = blockIdx.x;
    if (blk < 716) {
        int t = blk * 256 + threadIdx.x;
        if (t < 65536) {                                // WcatB rows 0..255 = outW
            WcatB[t] = f2bf(out_proj_w[t]);
        } else if (t < 139264) {                        // w1c_f8: K=288 N=256 (+spatial)
            int u = t - 65536;
            int e = u & 7, lane = (u >> 3) & 63, f = u >> 9;
            int l15 = lane & 15, quad = lane >> 4;
            int ct = f & 15, kc = f >> 4;               // kc 0..8
            int o = ct * 16 + l15, k = kc * 32 + quad * 8 + e;
            float v;
            if (k < 256)       v = w1[o * 771 + 512 + k];
            else if (k < 259)  v = w1[o * 771 + 768 + (k - 256)];
            else               v = 0.f;
            w1c_f8[u] = f2fp8(v);
        } else if (t < 172032) {                        // w2g_f8 = w2*ln_g, K=256 N=128
            int u = t - 139264;
            int e = u & 7, lane = (u >> 3) & 63, f = u >> 9;
            int l15 = lane & 15, quad = lane >> 4;
            int ct = f & 7, kc = f >> 3;
            int o = ct * 16 + l15, k = kc * 32 + quad * 8 + e;
            w2g_f8[u] = f2fp8(w2[o * 256 + k] * ln_g[k]);
        } else if (t < 180224) {                        // w3_f8 K=128 N=64
            int u = t - 172032;
            int e = u & 7, lane = (u >> 3) & 63, f = u >> 9;
            int l15 = lane & 15, quad = lane >> 4;
            int ct = f & 3, kc = f >> 2;
            int o = ct * 16 + l15, k = kc * 32 + quad * 8 + e;
            w3_f8[u] = f2fp8(w3[o * 128 + k]);
        } else if (t < 182272) {                        // w4_f8 K=64 N=32
            int u = t - 180224;
            int e = u & 7, lane = (u >> 3) & 63, f = u >> 9;
            int l15 = lane & 15, quad = lane >> 4;
            int ct = f & 1, kc = f >> 1;
            int o = ct * 16 + l15, k = kc * 32 + quad * 8 + e;
            w4_f8[u] = f2fp8(w4[o * 64 + k]);
        } else if (t < 183040) {                        // bias768
            int n = t - 182272;
            if (n < 256) bias768[n] = out_proj_b[n];
            else {
                int m = n - 256;
                float s = 0.f;
                for (int d = 0; d < 256; d += 4) {
                    float4 ob = *reinterpret_cast<const float4*>(&out_proj_b[d]);
                    const float* wr = (m < 256) ? &w1[m * 771 + d]
                                                : &w1[(m - 256) * 771 + 256 + d];
                    float4 w = *reinterpret_cast<const float4*>(wr);
                    s += ob.x * w.x + ob.y * w.y + ob.z * w.z + ob.w * w.w;
                }
                bias768[n] = s + ((m < 256) ? b1[m] : 0.f);
            }
        } else if (t < 183168) {                        // c1/c2 LN-fold constants
            int p = t - 183040;
            float s2 = 0.f, s1 = 0.f;
            for (int k = 0; k < 256; k += 4) {
                float4 w = *reinterpret_cast<const float4*>(&w2[p * 256 + k]);
                float4 g = *reinterpret_cast<const float4*>(&ln_g[k]);
                float4 lb = *reinterpret_cast<const float4*>(&ln_b[k]);
                s2 += g.x * w.x + g.y * w.y + g.z * w.z + g.w * w.w;
                s1 += lb.x * w.x + lb.y * w.y + lb.z * w.z + lb.w * w.w;
            }
            c2[p] = s2;
            c1[p] = s1 + b2[p];
        }
    } else if (blk < 1228) {
        // ---- Wcomb[n][e] = sum_d wAB[n][d] * outW[d][e] -> WcatB rows 256+n
        const int n = blk - 716, e = threadIdx.x;
        const float* wrow = (n < 256) ? &w1[n * 771] : &w1[(n - 256) * 771 + 256];
        float acc = 0.f;
        for (int d = 0; d < 256; d += 4) {
            float4 w = *reinterpret_cast<const float4*>(&wrow[d]);
            acc += w.x * out_proj_w[(d + 0) * 256 + e];
            acc += w.y * out_proj_w[(d + 1) * 256 + e];
            acc += w.z * out_proj_w[(d + 2) * 256 + e];
            acc += w.w * out_proj_w[(d + 3) * 256 + e];
        }
        WcatB[(256 + n) * 256 + e] = f2bf(acc);
    } else {
        // ---- qkv GEMM (raw fp32 inputs, inline cvt): 144 blocks, 64x64 ----
        const int q = blk - 1228;
        const int bm = q % 12, bn = q / 12;
        const int wv = threadIdx.x >> 6, lane = threadIdx.x & 63;
        const int l15 = lane & 15, quad = lane >> 4;
        const int row0 = bm * 64 + wv * 16;
        const int col0 = bn * 64;
        f32x4 acc[4] = {};
        for (int kc = 0; kc < 8; ++kc) {
            bf16x8 a = load8f_bf(&features[(row0 + l15) * 256 + kc * 32 + quad * 8]);
#pragma unroll
            for (int ct = 0; ct < 4; ++ct) {
                bf16x8 b = load8f_bf(&in_proj_w[(col0 + ct * 16 + l15) * 256 + kc * 32 + quad * 8]);
                acc[ct] = __builtin_amdgcn_mfma_f32_16x16x32_bf16(a, b, acc[ct], 0, 0, 0);
            }
        }
#pragma unroll
        for (int ct = 0; ct < 4; ++ct)
#pragma unroll
            for (int r = 0; r < 4; ++r) {
                int row = row0 + quad * 4 + r, col = col0 + ct * 16 + l15;
                float v = acc[ct][r] + in_proj_b[col];
                if (col < 512) qkvb[row * 768 + col] = f2bf(v);
                else           Vt[(col - 512) * 768 + row] = f2bf(v);
            }
    }
}

// ---------------- fused [att | AB] GEMM ------------------------------------
__global__ __launch_bounds__(256) void gemm_attab(
    const unsigned short* __restrict__ A, const unsigned short* __restrict__ W,
    const float* __restrict__ bias, float* __restrict__ att,
    float* __restrict__ AB)
{
    const int wv = threadIdx.x >> 6, lane = threadIdx.x & 63;
    const int l15 = lane & 15, quad = lane >> 4;
    const int row0 = blockIdx.x * 64 + wv * 16;
    const int col0 = blockIdx.y * 64;
    f32x4 acc[4] = {};
    for (int kc = 0; kc < 8; ++kc) {
        bf16x8 a = *reinterpret_cast<const bf16x8*>(&A[(row0 + l15) * 256 + kc * 32 + quad * 8]);
#pragma unroll
        for (int ct = 0; ct < 4; ++ct) {
            bf16x8 b = *reinterpret_cast<const bf16x8*>(&W[(col0 + ct * 16 + l15) * 256 + kc * 32 + quad * 8]);
            acc[ct] = __builtin_amdgcn_mfma_f32_16x16x32_bf16(a, b, acc[ct], 0, 0, 0);
        }
    }
#pragma unroll
    for (int ct = 0; ct < 4; ++ct)
#pragma unroll
        for (int r = 0; r < 4; ++r) {
            int row = row0 + quad * 4 + r, col = col0 + ct * 16 + l15;
            float v = acc[ct][r] + bias[col];
            if (col < 256) att[row * 256 + col] = v;
            else           AB[row * 512 + (col - 256)] = v;
        }
}

// ---------------- fused MFMA attention: 32-row q-tiles ---------------------
#define SP 776

__global__ __launch_bounds__(256) void attn_mfma(
    const unsigned short* __restrict__ qkvb, const unsigned short* __restrict__ Vt,
    unsigned short* __restrict__ Obf)
{
    __shared__ __align__(16) unsigned short smS[32 * SP];   // 49.7 KB
    const int h = blockIdx.x, q0 = blockIdx.y * 32, hb = h * 32;
    const int tid = threadIdx.x, wave = tid >> 6, lane = tid & 63;
    const int l15 = lane & 15, quad = lane >> 4;

    bf16x8 af[2];
#pragma unroll
    for (int mt = 0; mt < 2; ++mt)
        af[mt] = *reinterpret_cast<const bf16x8*>(&qkvb[(q0 + mt * 16 + l15) * 768 + hb + quad * 8]);
#pragma unroll
    for (int ct = 0; ct < 12; ++ct) {
        int n0 = wave * 192 + ct * 16;
        bf16x8 b = *reinterpret_cast<const bf16x8*>(&qkvb[(n0 + l15) * 768 + 256 + hb + quad * 8]);
#pragma unroll
        for (int mt = 0; mt < 2; ++mt) {
            f32x4 c = {};
            c = __builtin_amdgcn_mfma_f32_16x16x32_bf16(af[mt], b, c, 0, 0, 0);
#pragma unroll
            for (int r = 0; r < 4; ++r)
                smS[(mt * 16 + quad * 4 + r) * SP + n0 + l15] =
                    f2bf(c[r] * 0.17677669529663689f);
        }
    }
    __syncthreads();

    {   // row softmax: 8 threads per row, 96 cols each
        const int row = tid >> 3, part = tid & 7;
        unsigned short* rp = &smS[row * SP + part * 96];
        float mx = -3.0e38f;
#pragma unroll
        for (int c8 = 0; c8 < 12; ++c8) {
            uint4 v = *reinterpret_cast<const uint4*>(&rp[c8 * 8]);
            const unsigned short* pe = reinterpret_cast<const unsigned short*>(&v);
#pragma unroll
            for (int e = 0; e < 8; ++e) mx = fmaxf(mx, bf2f(pe[e]));
        }
        mx = fmaxf(mx, __shfl_xor(mx, 1, 64));
        mx = fmaxf(mx, __shfl_xor(mx, 2, 64));
        mx = fmaxf(mx, __shfl_xor(mx, 4, 64));
        float ls = 0.f;
#pragma unroll
        for (int c8 = 0; c8 < 12; ++c8) {
            uint4 v = *reinterpret_cast<const uint4*>(&rp[c8 * 8]);
            const unsigned short* pe = reinterpret_cast<const unsigned short*>(&v);
            unsigned short o8[8];
#pragma unroll
            for (int e = 0; e < 8; ++e) {
                float ev = __expf(bf2f(pe[e]) - mx);
                ls += ev;
                o8[e] = f2bf(ev);
            }
            *reinterpret_cast<uint4*>(&rp[c8 * 8]) = *reinterpret_cast<const uint4*>(o8);
        }
        ls += __shfl_xor(ls, 1, 64);
        ls += __shfl_xor(ls, 2, 64);
        ls += __shfl_xor(ls, 4, 64);
        float inv = 1.0f / ls;
#pragma unroll
        for (int c8 = 0; c8 < 12; ++c8) {
            uint4 v = *reinterpret_cast<const uint4*>(&rp[c8 * 8]);
            const unsigned short* pe = reinterpret_cast<const unsigned short*>(&v);
            unsigned short o8[8];
#pragma unroll
            for (int e = 0; e < 8; ++e) o8[e] = f2bf(bf2f(pe[e]) * inv);
            *reinterpret_cast<uint4*>(&rp[c8 * 8]) = *reinterpret_cast<const uint4*>(o8);
        }
    }
    __syncthreads();

    const int row0 = (wave >> 1) * 16, cg = wave & 1;
    f32x4 accp = {};
    for (int kc = 0; kc < 24; ++kc) {
        bf16x8 a = *reinterpret_cast<const bf16x8*>(&smS[(row0 + l15) * SP + kc * 32 + quad * 8]);
        bf16x8 b = *reinterpret_cast<const bf16x8*>(&Vt[(hb + cg * 16 + l15) * 768 + kc * 32 + quad * 8]);
        accp = __builtin_amdgcn_mfma_f32_16x16x32_bf16(a, b, accp, 0, 0, 0);
    }
#pragma unroll
    for (int r = 0; r < 4; ++r) {
        int row = q0 + row0 + quad * 4 + r;
        Obf[row * 256 + hb + cg * 16 + l15] = f2bf(accp[r]);
    }
}

// ---------------- fused pair MLP (transposed, fp8 16x16), 1 i x 64 j -------
#define S1 296   // scaledA/h1 row stride (288 fp8 + 8 pad)
#define S2 136   // h2 row stride
#define S3 72    // h3 row stride

__global__ __launch_bounds__(256, 4) void pair_mlp(
    const float* __restrict__ att, const float* __restrict__ AB,
    const unsigned char* __restrict__ w1c_f8, const unsigned char* __restrict__ w2g_f8,
    const unsigned char* __restrict__ w3_f8, const unsigned char* __restrict__ w4_f8,
    const float* __restrict__ boxes,
    const float* __restrict__ c1, const float* __restrict__ c2,
    const float* __restrict__ b3, const float* __restrict__ b4,
    const float* __restrict__ w5, const float* __restrict__ b5,
    float* __restrict__ out)
{
    __shared__ __align__(16) unsigned char smH[64 * S1];    // scaledA -> h1
    __shared__ __align__(16) unsigned char smH2[64 * S2];   // h2
    __shared__ __align__(16) unsigned char smH3[64 * S3];   // h3
    __shared__ float s_psum[64][4], s_pssq[64][4];
    __shared__ float s_mu[64], s_rs[64];
    __shared__ float s_l5[64][2];

    const int i    = blockIdx.x;
    const int j0   = blockIdx.y * 64;
    const int tid  = threadIdx.x;
    const int wave = tid >> 6;
    const int lane = tid & 63;
    const int l15  = lane & 15;
    const int quad = lane >> 4;

    // ---- stage scaledA fp8 from f32 att (no unpack) ----
    {
        const int g = tid & 63;
        float4 fi4 = *reinterpret_cast<const float4*>(&att[i * 256 + g * 4]);
#pragma unroll
        for (int it = 0; it < 16; ++it) {
            int r = (tid >> 6) + it * 4;
            float4 aj = *reinterpret_cast<const float4*>(&att[(j0 + r) * 256 + g * 4]);
            *reinterpret_cast<int*>(&smH[r * S1 + g * 4]) =
                pk4_fp8(aj.x * fi4.x, aj.y * fi4.y, aj.z * fi4.z, aj.w * fi4.w);
        }
    }
    if (tid < 64) {   // spatial tail cols 256..287
        int j = j0 + tid;
        float xd = fabsf(boxes[i * 4 + 0] - boxes[j * 4 + 0]);
        float yd = boxes[i * 4 + 1] - boxes[j * 4 + 1];
        *reinterpret_cast<int*>(&smH[tid * S1 + 256]) = pk4_fp8(xd, fabsf(yd), yd, 0.f);
        *reinterpret_cast<int*>(&smH[tid * S1 + 260]) = 0;
        *reinterpret_cast<long long*>(&smH[tid * S1 + 264]) = 0;
        *reinterpret_cast<long long*>(&smH[tid * S1 + 272]) = 0;
        *reinterpret_cast<long long*>(&smH[tid * S1 + 280]) = 0;
    }
    __syncthreads();                                          // B0

    // ======== GEMM1 (16x16x32 fp8, K=288): wave owns o-slice 64 ========
    f32x4 acc1[4][4] = {};   // [mt (o)][nt (j)]
    for (int kc = 0; kc < 9; ++kc) {
        long long a[4];
#pragma unroll
        for (int mt = 0; mt < 4; ++mt)
            a[mt] = *reinterpret_cast<const long long*>(&w1c_f8[((kc * 16 + wave * 4 + mt) * 64 + lane) * 8]);
#pragma unroll
        for (int nt = 0; nt < 4; ++nt) {
            long long b = *reinterpret_cast<const long long*>(&smH[(nt * 16 + l15) * S1 + kc * 32 + quad * 8]);
#pragma unroll
            for (int mt = 0; mt < 4; ++mt)
                acc1[mt][nt] = __builtin_amdgcn_mfma_f32_16x16x32_fp8_fp8(a[mt], b, acc1[mt][nt], 0, 0, 0);
        }
    }

    // ---- epilogue1: + A_i[o] + B_j[o], relu, stats ----
    const int o0 = wave * 64;
    float vsum[4] = {}, vssq[4] = {};
#pragma unroll
    for (int mt = 0; mt < 4; ++mt) {
        int o = o0 + mt * 16 + quad * 4;
        float4 Ai = *reinterpret_cast<const float4*>(&AB[i * 512 + o]);
        float AiA[4] = {Ai.x, Ai.y, Ai.z, Ai.w};
#pragma unroll
        for (int nt = 0; nt < 4; ++nt) {
            int j = nt * 16 + l15;
            float4 Bj = *reinterpret_cast<const float4*>(&AB[(j0 + j) * 512 + 256 + o]);
            float BjA[4] = {Bj.x, Bj.y, Bj.z, Bj.w};
#pragma unroll
            for (int r = 0; r < 4; ++r) {
                float v = fmaxf(acc1[mt][nt][r] + AiA[r] + BjA[r], 0.f);
                acc1[mt][nt][r] = v;
                vsum[nt] += v; vssq[nt] += v * v;
            }
        }
    }
#pragma unroll
    for (int nt = 0; nt < 4; ++nt) {
        vsum[nt] += __shfl_xor(vsum[nt], 16, 64);
        vsum[nt] += __shfl_xor(vsum[nt], 32, 64);
        vssq[nt] += __shfl_xor(vssq[nt], 16, 64);
        vssq[nt] += __shfl_xor(vssq[nt], 32, 64);
    }
    if (quad == 0)
#pragma unroll
        for (int nt = 0; nt < 4; ++nt) {
            s_psum[nt * 16 + l15][wave] = vsum[nt];
            s_pssq[nt * 16 + l15][wave] = vssq[nt];
        }
    __syncthreads();                                          // B1: GEMM1 reads done
    // h1 fp8 write into smH (overwrites scaledA; WAR cleared by B1)
#pragma unroll
    for (int mt = 0; mt < 4; ++mt) {
        int o = o0 + mt * 16 + quad * 4;
#pragma unroll
        for (int nt = 0; nt < 4; ++nt) {
            int j = nt * 16 + l15;
            *reinterpret_cast<int*>(&smH[j * S1 + o]) =
                pk4_fp8(acc1[mt][nt][0], acc1[mt][nt][1], acc1[mt][nt][2], acc1[mt][nt][3]);
        }
    }
    if (wave == 0) {   // finalize LN stats
        int j = lane;
        float sm = (s_psum[j][0] + s_psum[j][1] + s_psum[j][2] + s_psum[j][3]) * (1.0f / 256.0f);
        float sq = (s_pssq[j][0] + s_pssq[j][1] + s_pssq[j][2] + s_pssq[j][3]) * (1.0f / 256.0f);
        s_mu[j] = sm;
        s_rs[j] = rsqrtf(sq - sm * sm + 1e-5f);
    }
    __syncthreads();                                          // B2: h1 + stats ready

    // ======== GEMM2 (16x16x32 fp8, K=256): wave owns p-slice 32 ========
    f32x4 acc2[2][4] = {};
    for (int kc = 0; kc < 8; ++kc) {
        long long a[2];
#pragma unroll
        for (int mt = 0; mt < 2; ++mt)
            a[mt] = *reinterpret_cast<const long long*>(&w2g_f8[((kc * 8 + wave * 2 + mt) * 64 + lane) * 8]);
#pragma unroll
        for (int nt = 0; nt < 4; ++nt) {
            long long b = *reinterpret_cast<const long long*>(&smH[(nt * 16 + l15) * S1 + kc * 32 + quad * 8]);
#pragma unroll
            for (int mt = 0; mt < 2; ++mt)
                acc2[mt][nt] = __builtin_amdgcn_mfma_f32_16x16x32_fp8_fp8(a[mt], b, acc2[mt][nt], 0, 0, 0);
        }
    }
    // epilogue2: LN-folded affine + relu -> h2 (separate region, no barrier)
#pragma unroll
    for (int mt = 0; mt < 2; ++mt) {
        int p = wave * 32 + mt * 16 + quad * 4;
        float4 C1 = *reinterpret_cast<const float4*>(&c1[p]);
        float4 C2 = *reinterpret_cast<const float4*>(&c2[p]);
        float C1A[4] = {C1.x, C1.y, C1.z, C1.w};
        float C2A[4] = {C2.x, C2.y, C2.z, C2.w};
#pragma unroll
        for (int nt = 0; nt < 4; ++nt) {
            int j = nt * 16 + l15;
            float mu = s_mu[j], rs = s_rs[j];
            float vv[4];
#pragma unroll
            for (int r = 0; r < 4; ++r)
                vv[r] = fmaxf(rs * (acc2[mt][nt][r] - mu * C2A[r]) + C1A[r], 0.f);
            *reinterpret_cast<int*>(&smH2[j * S2 + p]) = pk4_fp8(vv[0], vv[1], vv[2], vv[3]);
        }
    }
    __syncthreads();                                          // B3: h2 ready

    // ======== GEMM3 (16x16x32 fp8, K=128) ========
    f32x4 acc3[4] = {};
    for (int kc = 0; kc < 4; ++kc) {
        long long a = *reinterpret_cast<const long long*>(&w3_f8[((kc * 4 + wave) * 64 + lane) * 8]);
#pragma unroll
        for (int nt = 0; nt < 4; ++nt) {
            long long b = *reinterpret_cast<const long long*>(&smH2[(nt * 16 + l15) * S2 + kc * 32 + quad * 8]);
            acc3[nt] = __builtin_amdgcn_mfma_f32_16x16x32_fp8_fp8(a, b, acc3[nt], 0, 0, 0);
        }
    }
    {   // epilogue3 -> h3 (separate region, no pre-barrier)
        int q = wave * 16 + quad * 4;
        float4 B3 = *reinterpret_cast<const float4*>(&b3[q]);
        float B3A[4] = {B3.x, B3.y, B3.z, B3.w};
#pragma unroll
        for (int nt = 0; nt < 4; ++nt) {
            int j = nt * 16 + l15;
            float vv[4];
#pragma unroll
            for (int r = 0; r < 4; ++r)
                vv[r] = fmaxf(acc3[nt][r] + B3A[r], 0.f);
            *reinterpret_cast<int*>(&smH3[j * S3 + q]) = pk4_fp8(vv[0], vv[1], vv[2], vv[3]);
        }
    }
    __syncthreads();                                          // B4: h3 ready

    // ======== GEMM4 (16x16x32 fp8, K=64) + head ========
    const int mt4 = wave & 1;
    const int jh  = wave >> 1;
    f32x4 acc4[2] = {};
#pragma unroll
    for (int kc = 0; kc < 2; ++kc) {
        long long a = *reinterpret_cast<const long long*>(&w4_f8[((kc * 2 + mt4) * 64 + lane) * 8]);
#pragma unroll
        for (int nt = 0; nt < 2; ++nt) {
            int j = jh * 32 + nt * 16 + l15;
            long long b = *reinterpret_cast<const long long*>(&smH3[j * S3 + kc * 32 + quad * 8]);
            acc4[nt] = __builtin_amdgcn_mfma_f32_16x16x32_fp8_fp8(a, b, acc4[nt], 0, 0, 0);
        }
    }
    {
        int o4 = mt4 * 16 + quad * 4;
        float4 B4 = *reinterpret_cast<const float4*>(&b4[o4]);
        float4 W5 = *reinterpret_cast<const float4*>(&w5[o4]);
        float B4A[4] = {B4.x, B4.y, B4.z, B4.w};
        float W5A[4] = {W5.x, W5.y, W5.z, W5.w};
#pragma unroll
        for (int nt = 0; nt < 2; ++nt) {
            float part = 0.f;
#pragma unroll
            for (int r = 0; r < 4; ++r)
                part += fmaxf(acc4[nt][r] + B4A[r], 0.f) * W5A[r];
            part += __shfl_xor(part, 16, 64);
            part += __shfl_xor(part, 32, 64);
            if (quad == 0)
                s_l5[jh * 32 + nt * 16 + l15][mt4] = part;
        }
    }
    __syncthreads();                                          // B5
    if (tid < 64) {
        int j = j0 + tid;
        float v = s_l5[tid][0] + s_l5[tid][1] + b5[0];
        out[i * 768 + j] = (j == i) ? -1.0e9f : v;
    }
}

// ---------------------------------------------------------------------------
extern "C" void kernel_launch(void* const* d_in, const int* in_sizes, int n_in,
                              void* d_out, int out_size, void* d_ws, size_t ws_size,
                              hipStream_t stream)
{
    const float* features   = (const float*)d_in[0];
    const float* boxes      = (const float*)d_in[1];
    const float* in_proj_w  = (const float*)d_in[2];
    const float* in_proj_b  = (const float*)d_in[3];
    const float* out_proj_w = (const float*)d_in[4];
    const float* out_proj_b = (const float*)d_in[5];
    const float* w1  = (const float*)d_in[6];
    const float* b1  = (const float*)d_in[7];
    const float* ln_g = (const float*)d_in[8];
    const float* ln_b = (const float*)d_in[9];
    const float* w2  = (const float*)d_in[10];
    const float* b2  = (const float*)d_in[11];
    const float* w3  = (const float*)d_in[12];
    const float* b3  = (const float*)d_in[13];
    const float* w4  = (const float*)d_in[14];
    const float* b4  = (const float*)d_in[15];
    const float* w5  = (const float*)d_in[16];
    const float* b5  = (const float*)d_in[17];
    float* out = (float*)d_out;

    // ---- workspace layout ----
    char* p = (char*)d_ws;
    unsigned short* qkvb  = (unsigned short*)p; p += 768 * 768 * 2;
    unsigned short* Vt    = (unsigned short*)p; p += 256 * 768 * 2;
    unsigned short* Obf   = (unsigned short*)p; p += 768 * 256 * 2;
    unsigned short* WcatB = (unsigned short*)p; p += 196608 * 2;   // [outW;Wcomb]
    float* att = (float*)p; p += 768 * 256 * 4;
    float* AB  = (float*)p; p += 768 * 512 * 4;
    unsigned char* w1c_f8  = (unsigned char*)p; p += 73728;
    unsigned char* w2g_f8  = (unsigned char*)p; p += 32768;
    unsigned char* w3_f8   = (unsigned char*)p; p += 8192;
    unsigned char* w4_f8   = (unsigned char*)p; p += 2048;
    float* bias768 = (float*)p; p += 768 * 4;
    float* c1v     = (float*)p; p += 128 * 4;
    float* c2v     = (float*)p; p += 128 * 4;

    // 1) pack + Wcomb + qkv GEMM
    pack_all<<<dim3(1372), dim3(256), 0, stream>>>(features, in_proj_w,
        in_proj_b, out_proj_w, w1, w2, w3, w4, b1, ln_g, ln_b, b2, out_proj_b,
        qkvb, Vt, WcatB, w1c_f8, w2g_f8, w3_f8, w4_f8, bias768, c1v, c2v);
    // 2) attention
    attn_mfma<<<dim3(8, 24), dim3(256), 0, stream>>>(qkvb, Vt, Obf);
    // 3) [att | AB] = O @ WcatB^T + bias768
    gemm_attab<<<dim3(12, 12), dim3(256), 0, stream>>>(Obf, WcatB, bias768,
        att, AB);
    // 4) pair MLP
    pair_mlp<<<dim3(768, 12), dim3(256), 0, stream>>>(att, AB,
        w1c_f8, w2g_f8, w3_f8, w4_f8, boxes, c1v, c2v,
        b3, b4, w5, b5, out);
}

// Round 9
// 291.081 us; speedup vs baseline: 1.2990x; 1.0347x over previous
//
#include <hip/hip_runtime.h>

// ---------------------------------------------------------------------------
// ImprovedLinkingPredictor round 9.
// - pair_mlp GEMM1/2/3 on MX-scaled fp8 (mfma_scale_f32_16x16x128_f8f6f4,
//   scales = 1.0): 2x rate of non-scaled fp8 -> MFMA pipe cycles halve.
//   GEMM1 spatial tail (k 256..287) via one 16x16x32 fp8 step; GEMM4 stays
//   16x16x32. C/D layout is shape-determined -> epilogues unchanged.
// - Strides 16B-aligned for 32B/lane fragment reads (S1=304, S2=144).
// - Front-end identical to round 8.
// ---------------------------------------------------------------------------

typedef __attribute__((ext_vector_type(8))) __bf16 bf16x8;    // bf16 MFMA frag
typedef __attribute__((ext_vector_type(4))) float f32x4;      // 16x16 C/D
typedef __attribute__((ext_vector_type(8))) int i32x8;        // 32B fp8 frag

__device__ __forceinline__ float bf2f(unsigned short u) {
    return __uint_as_float(((unsigned int)u) << 16);
}
__device__ __forceinline__ unsigned short f2bf(float f) {
    union { __bf16 b; unsigned short u; } cv;
    cv.b = (__bf16)f;
    return cv.u;
}
__device__ __forceinline__ unsigned pk2(float lo, float hi) {
    return (unsigned)f2bf(lo) | ((unsigned)f2bf(hi) << 16);
}
__device__ __forceinline__ int pk4_fp8(float a, float b, float c, float d) {
    int w = __builtin_amdgcn_cvt_pk_fp8_f32(a, b, 0, false);
    w = __builtin_amdgcn_cvt_pk_fp8_f32(c, d, w, true);
    return w;
}
__device__ __forceinline__ unsigned char f2fp8(float v) {
    return (unsigned char)(__builtin_amdgcn_cvt_pk_fp8_f32(v, 0.f, 0, false) & 0xff);
}
__device__ __forceinline__ bf16x8 load8f_bf(const float* p) {
    float4 a = *reinterpret_cast<const float4*>(p);
    float4 b = *reinterpret_cast<const float4*>(p + 4);
    union { bf16x8 v; unsigned u[4]; } cv;
    cv.u[0] = pk2(a.x, a.y); cv.u[1] = pk2(a.z, a.w);
    cv.u[2] = pk2(b.x, b.y); cv.u[3] = pk2(b.z, b.w);
    return cv.v;
}
__device__ __forceinline__ i32x8 ld32_lds(const unsigned char* p) {
    union { i32x8 v; uint4 q[2]; } r;
    r.q[0] = *reinterpret_cast<const uint4*>(p);
    r.q[1] = *reinterpret_cast<const uint4*>(p + 16);
    return r.v;
}
#define SC1 0x7F7F7F7F   // e8m0 scale = 1.0 in all bytes
#define MFMA_MX(a, b, c) __builtin_amdgcn_mfma_scale_f32_16x16x128_f8f6f4( \
        (a), (b), (c), 0, 0, 0, SC1, 0, SC1)

// ---------------- pack_all: packing + Wcomb + qkv GEMM ---------------------
// MX frag-major (K=128/lane=32B): elem (o,k) at ((ks*NT + o>>4)*64 + lane)*32
//   + (k&31), lane = (o&15) | (((k>>5)&3)<<4), ks = k>>7.
// 16x16x32 frag-major (tail/w4): ((f)*64 + lane)*8 + (k&7),
//   lane = (o&15) | (((k>>3)&3)<<4).
__global__ __launch_bounds__(256) void pack_all(
    const float* __restrict__ features, const float* __restrict__ in_proj_w,
    const float* __restrict__ in_proj_b, const float* __restrict__ out_proj_w,
    const float* __restrict__ w1, const float* __restrict__ w2,
    const float* __restrict__ w3, const float* __restrict__ w4,
    const float* __restrict__ b1, const float* __restrict__ ln_g,
    const float* __restrict__ ln_b, const float* __restrict__ b2,
    const float* __restrict__ out_proj_b,
    unsigned short* __restrict__ qkvb, unsigned short* __restrict__ Vt,
    unsigned short* __restrict__ WcatB,
    unsigned char* __restrict__ w1c_mx, unsigned char* __restrict__ w1t_f8,
    unsigned char* __restrict__ w2g_mx, unsigned char* __restrict__ w3_mx,
    unsigned char* __restrict__ w4_f8,
    float* __restrict__ bias768, float* __restrict__ c1, float* __restrict__ c2)
{
    const int blk = blockIdx.x;
    if (blk < 716) {
        int t = blk * 256 + threadIdx.x;
        if (t < 65536) {                                // WcatB rows 0..255 = outW
            WcatB[t] = f2bf(out_proj_w[t]);
        } else if (t < 131072) {                        // w1c_mx: K=256 N=256, MX frag
            int u = t - 65536;
            int e = u & 31, lane = (u >> 5) & 63, f = u >> 11;
            int mt = f & 15, ks = f >> 4;
            int o = mt * 16 + (lane & 15);
            int k = ks * 128 + ((lane >> 4) & 3) * 32 + e;
            w1c_mx[u] = f2fp8(w1[o * 771 + 512 + k]);
        } else if (t < 139264) {                        // w1t_f8: spatial tail k=256..287
            int u = t - 131072;
            int e = u & 7, lane = (u >> 3) & 63, f = u >> 9;
            int o = f * 16 + (lane & 15);
            int k = ((lane >> 4) & 3) * 8 + e;          // 0..31 within tail
            float v = (k < 3) ? w1[o * 771 + 768 + k] : 0.f;
            w1t_f8[u] = f2fp8(v);
        } else if (t < 172032) {                        // w2g_mx = w2*ln_g, K=256 N=128
            int u = t - 139264;
            int e = u & 31, lane = (u >> 5) & 63, f = u >> 11;
            int mt = f & 7, ks = f >> 3;
            int p = mt * 16 + (lane & 15);
            int k = ks * 128 + ((lane >> 4) & 3) * 32 + e;
            w2g_mx[u] = f2fp8(w2[p * 256 + k] * ln_g[k]);
        } else if (t < 180224) {                        // w3_mx: K=128 N=64
            int u = t - 172032;
            int e = u & 31, lane = (u >> 5) & 63, f = u >> 11;
            int o = f * 16 + (lane & 15);
            int k = ((lane >> 4) & 3) * 32 + e;
            w3_mx[u] = f2fp8(w3[o * 128 + k]);
        } else if (t < 182272) {                        // w4_f8 K=64 N=32 (16x16x32)
            int u = t - 180224;
            int e = u & 7, lane = (u >> 3) & 63, f = u >> 9;
            int l15 = lane & 15, quad = lane >> 4;
            int ct = f & 1, kc = f >> 1;
            int o = ct * 16 + l15, k = kc * 32 + quad * 8 + e;
            w4_f8[u] = f2fp8(w4[o * 64 + k]);
        } else if (t < 183040) {                        // bias768
            int n = t - 182272;
            if (n < 256) bias768[n] = out_proj_b[n];
            else {
                int m = n - 256;
                float s = 0.f;
                for (int d = 0; d < 256; d += 4) {
                    float4 ob = *reinterpret_cast<const float4*>(&out_proj_b[d]);
                    const float* wr = (m < 256) ? &w1[m * 771 + d]
                                                : &w1[(m - 256) * 771 + 256 + d];
                    float4 w = *reinterpret_cast<const float4*>(wr);
                    s += ob.x * w.x + ob.y * w.y + ob.z * w.z + ob.w * w.w;
                }
                bias768[n] = s + ((m < 256) ? b1[m] : 0.f);
            }
        } else if (t < 183168) {                        // c1/c2 LN-fold constants
            int p = t - 183040;
            float s2 = 0.f, s1 = 0.f;
            for (int k = 0; k < 256; k += 4) {
                float4 w = *reinterpret_cast<const float4*>(&w2[p * 256 + k]);
                float4 g = *reinterpret_cast<const float4*>(&ln_g[k]);
                float4 lb = *reinterpret_cast<const float4*>(&ln_b[k]);
                s2 += g.x * w.x + g.y * w.y + g.z * w.z + g.w * w.w;
                s1 += lb.x * w.x + lb.y * w.y + lb.z * w.z + lb.w * w.w;
            }
            c2[p] = s2;
            c1[p] = s1 + b2[p];
        }
    } else if (blk < 1228) {
        // ---- Wcomb[n][e] = sum_d wAB[n][d] * outW[d][e] -> WcatB rows 256+n
        const int n = blk - 716, e = threadIdx.x;
        const float* wrow = (n < 256) ? &w1[n * 771] : &w1[(n - 256) * 771 + 256];
        float acc = 0.f;
        for (int d = 0; d < 256; d += 4) {
            float4 w = *reinterpret_cast<const float4*>(&wrow[d]);
            acc += w.x * out_proj_w[(d + 0) * 256 + e];
            acc += w.y * out_proj_w[(d + 1) * 256 + e];
            acc += w.z * out_proj_w[(d + 2) * 256 + e];
            acc += w.w * out_proj_w[(d + 3) * 256 + e];
        }
        WcatB[(256 + n) * 256 + e] = f2bf(acc);
    } else {
        // ---- qkv GEMM (raw fp32 inputs, inline cvt): 144 blocks, 64x64 ----
        const int q = blk - 1228;
        const int bm = q % 12, bn = q / 12;
        const int wv = threadIdx.x >> 6, lane = threadIdx.x & 63;
        const int l15 = lane & 15, quad = lane >> 4;
        const int row0 = bm * 64 + wv * 16;
        const int col0 = bn * 64;
        f32x4 acc[4] = {};
        for (int kc = 0; kc < 8; ++kc) {
            bf16x8 a = load8f_bf(&features[(row0 + l15) * 256 + kc * 32 + quad * 8]);
#pragma unroll
            for (int ct = 0; ct < 4; ++ct) {
                bf16x8 b = load8f_bf(&in_proj_w[(col0 + ct * 16 + l15) * 256 + kc * 32 + quad * 8]);
                acc[ct] = __builtin_amdgcn_mfma_f32_16x16x32_bf16(a, b, acc[ct], 0, 0, 0);
            }
        }
#pragma unroll
        for (int ct = 0; ct < 4; ++ct)
#pragma unroll
            for (int r = 0; r < 4; ++r) {
                int row = row0 + quad * 4 + r, col = col0 + ct * 16 + l15;
                float v = acc[ct][r] + in_proj_b[col];
                if (col < 512) qkvb[row * 768 + col] = f2bf(v);
                else           Vt[(col - 512) * 768 + row] = f2bf(v);
            }
    }
}

// ---------------- fused [att | AB] GEMM ------------------------------------
__global__ __launch_bounds__(256) void gemm_attab(
    const unsigned short* __restrict__ A, const unsigned short* __restrict__ W,
    const float* __restrict__ bias, float* __restrict__ att,
    float* __restrict__ AB)
{
    const int wv = threadIdx.x >> 6, lane = threadIdx.x & 63;
    const int l15 = lane & 15, quad = lane >> 4;
    const int row0 = blockIdx.x * 64 + wv * 16;
    const int col0 = blockIdx.y * 64;
    f32x4 acc[4] = {};
    for (int kc = 0; kc < 8; ++kc) {
        bf16x8 a = *reinterpret_cast<const bf16x8*>(&A[(row0 + l15) * 256 + kc * 32 + quad * 8]);
#pragma unroll
        for (int ct = 0; ct < 4; ++ct) {
            bf16x8 b = *reinterpret_cast<const bf16x8*>(&W[(col0 + ct * 16 + l15) * 256 + kc * 32 + quad * 8]);
            acc[ct] = __builtin_amdgcn_mfma_f32_16x16x32_bf16(a, b, acc[ct], 0, 0, 0);
        }
    }
#pragma unroll
    for (int ct = 0; ct < 4; ++ct)
#pragma unroll
        for (int r = 0; r < 4; ++r) {
            int row = row0 + quad * 4 + r, col = col0 + ct * 16 + l15;
            float v = acc[ct][r] + bias[col];
            if (col < 256) att[row * 256 + col] = v;
            else           AB[row * 512 + (col - 256)] = v;
        }
}

// ---------------- fused MFMA attention: 32-row q-tiles ---------------------
#define SP 776

__global__ __launch_bounds__(256) void attn_mfma(
    const unsigned short* __restrict__ qkvb, const unsigned short* __restrict__ Vt,
    unsigned short* __restrict__ Obf)
{
    __shared__ __align__(16) unsigned short smS[32 * SP];   // 49.7 KB
    const int h = blockIdx.x, q0 = blockIdx.y * 32, hb = h * 32;
    const int tid = threadIdx.x, wave = tid >> 6, lane = tid & 63;
    const int l15 = lane & 15, quad = lane >> 4;

    bf16x8 af[2];
#pragma unroll
    for (int mt = 0; mt < 2; ++mt)
        af[mt] = *reinterpret_cast<const bf16x8*>(&qkvb[(q0 + mt * 16 + l15) * 768 + hb + quad * 8]);
#pragma unroll
    for (int ct = 0; ct < 12; ++ct) {
        int n0 = wave * 192 + ct * 16;
        bf16x8 b = *reinterpret_cast<const bf16x8*>(&qkvb[(n0 + l15) * 768 + 256 + hb + quad * 8]);
#pragma unroll
        for (int mt = 0; mt < 2; ++mt) {
            f32x4 c = {};
            c = __builtin_amdgcn_mfma_f32_16x16x32_bf16(af[mt], b, c, 0, 0, 0);
#pragma unroll
            for (int r = 0; r < 4; ++r)
                smS[(mt * 16 + quad * 4 + r) * SP + n0 + l15] =
                    f2bf(c[r] * 0.17677669529663689f);
        }
    }
    __syncthreads();

    {   // row softmax: 8 threads per row, 96 cols each
        const int row = tid >> 3, part = tid & 7;
        unsigned short* rp = &smS[row * SP + part * 96];
        float mx = -3.0e38f;
#pragma unroll
        for (int c8 = 0; c8 < 12; ++c8) {
            uint4 v = *reinterpret_cast<const uint4*>(&rp[c8 * 8]);
            const unsigned short* pe = reinterpret_cast<const unsigned short*>(&v);
#pragma unroll
            for (int e = 0; e < 8; ++e) mx = fmaxf(mx, bf2f(pe[e]));
        }
        mx = fmaxf(mx, __shfl_xor(mx, 1, 64));
        mx = fmaxf(mx, __shfl_xor(mx, 2, 64));
        mx = fmaxf(mx, __shfl_xor(mx, 4, 64));
        float ls = 0.f;
#pragma unroll
        for (int c8 = 0; c8 < 12; ++c8) {
            uint4 v = *reinterpret_cast<const uint4*>(&rp[c8 * 8]);
            const unsigned short* pe = reinterpret_cast<const unsigned short*>(&v);
            unsigned short o8[8];
#pragma unroll
            for (int e = 0; e < 8; ++e) {
                float ev = __expf(bf2f(pe[e]) - mx);
                ls += ev;
                o8[e] = f2bf(ev);
            }
            *reinterpret_cast<uint4*>(&rp[c8 * 8]) = *reinterpret_cast<const uint4*>(o8);
        }
        ls += __shfl_xor(ls, 1, 64);
        ls += __shfl_xor(ls, 2, 64);
        ls += __shfl_xor(ls, 4, 64);
        float inv = 1.0f / ls;
#pragma unroll
        for (int c8 = 0; c8 < 12; ++c8) {
            uint4 v = *reinterpret_cast<const uint4*>(&rp[c8 * 8]);
            const unsigned short* pe = reinterpret_cast<const unsigned short*>(&v);
            unsigned short o8[8];
#pragma unroll
            for (int e = 0; e < 8; ++e) o8[e] = f2bf(bf2f(pe[e]) * inv);
            *reinterpret_cast<uint4*>(&rp[c8 * 8]) = *reinterpret_cast<const uint4*>(o8);
        }
    }
    __syncthreads();

    const int row0 = (wave >> 1) * 16, cg = wave & 1;
    f32x4 accp = {};
    for (int kc = 0; kc < 24; ++kc) {
        bf16x8 a = *reinterpret_cast<const bf16x8*>(&smS[(row0 + l15) * SP + kc * 32 + quad * 8]);
        bf16x8 b = *reinterpret_cast<const bf16x8*>(&Vt[(hb + cg * 16 + l15) * 768 + kc * 32 + quad * 8]);
        accp = __builtin_amdgcn_mfma_f32_16x16x32_bf16(a, b, accp, 0, 0, 0);
    }
#pragma unroll
    for (int r = 0; r < 4; ++r) {
        int row = q0 + row0 + quad * 4 + r;
        Obf[row * 256 + hb + cg * 16 + l15] = f2bf(accp[r]);
    }
}

// ---------------- fused pair MLP (MX fp8), 1 i x 64 j ----------------------
#define S1 304   // scaledA/h1 row stride: 288 data + 16 pad (16B aligned)
#define S2 144   // h2 row stride: 128 data + 16 pad
#define S3 72    // h3 row stride: 64 data + 8 pad

__global__ __launch_bounds__(256, 4) void pair_mlp(
    const float* __restrict__ att, const float* __restrict__ AB,
    const unsigned char* __restrict__ w1c_mx, const unsigned char* __restrict__ w1t_f8,
    const unsigned char* __restrict__ w2g_mx, const unsigned char* __restrict__ w3_mx,
    const unsigned char* __restrict__ w4_f8,
    const float* __restrict__ boxes,
    const float* __restrict__ c1, const float* __restrict__ c2,
    const float* __restrict__ b3, const float* __restrict__ b4,
    const float* __restrict__ w5, const float* __restrict__ b5,
    float* __restrict__ out)
{
    __shared__ __align__(16) unsigned char smH[64 * S1];    // scaledA -> h1 (19.0 KB)
    __shared__ __align__(16) unsigned char smH2[64 * S2];   // h2 (9.2 KB)
    __shared__ __align__(16) unsigned char smH3[64 * S3];   // h3 (4.6 KB)
    __shared__ float s_psum[64][4], s_pssq[64][4];
    __shared__ float s_mu[64], s_rs[64];
    __shared__ float s_l5[64][2];

    const int i    = blockIdx.x;
    const int j0   = blockIdx.y * 64;
    const int tid  = threadIdx.x;
    const int wave = tid >> 6;
    const int lane = tid & 63;
    const int l15  = lane & 15;
    const int quad = lane >> 4;

    // ---- stage scaledA fp8 from f32 att ----
    {
        const int g = tid & 63;
        float4 fi4 = *reinterpret_cast<const float4*>(&att[i * 256 + g * 4]);
#pragma unroll
        for (int it = 0; it < 16; ++it) {
            int r = (tid >> 6) + it * 4;
            float4 aj = *reinterpret_cast<const float4*>(&att[(j0 + r) * 256 + g * 4]);
            *reinterpret_cast<int*>(&smH[r * S1 + g * 4]) =
                pk4_fp8(aj.x * fi4.x, aj.y * fi4.y, aj.z * fi4.z, aj.w * fi4.w);
        }
    }
    if (tid < 64) {   // spatial tail cols 256..287 (288..303 pad, never read)
        int j = j0 + tid;
        float xd = fabsf(boxes[i * 4 + 0] - boxes[j * 4 + 0]);
        float yd = boxes[i * 4 + 1] - boxes[j * 4 + 1];
        *reinterpret_cast<int*>(&smH[tid * S1 + 256]) = pk4_fp8(xd, fabsf(yd), yd, 0.f);
        *reinterpret_cast<int*>(&smH[tid * S1 + 260]) = 0;
        *reinterpret_cast<long long*>(&smH[tid * S1 + 264]) = 0;
        *reinterpret_cast<long long*>(&smH[tid * S1 + 272]) = 0;
        *reinterpret_cast<long long*>(&smH[tid * S1 + 280]) = 0;
    }
    __syncthreads();                                          // B0

    // ======== GEMM1: 2x MX(K=128) + 16x16x32 tail; wave owns o-slice 64 ====
    f32x4 acc1[4][4] = {};   // [mt (o)][nt (j)]
#pragma unroll
    for (int ks = 0; ks < 2; ++ks) {
        i32x8 a[4];
#pragma unroll
        for (int mt = 0; mt < 4; ++mt)
            a[mt] = *reinterpret_cast<const i32x8*>(&w1c_mx[((ks * 16 + wave * 4 + mt) * 64 + lane) * 32]);
#pragma unroll
        for (int nt = 0; nt < 4; ++nt) {
            i32x8 b = ld32_lds(&smH[(nt * 16 + l15) * S1 + ks * 128 + quad * 32]);
#pragma unroll
            for (int mt = 0; mt < 4; ++mt)
                acc1[mt][nt] = MFMA_MX(a[mt], b, acc1[mt][nt]);
        }
    }
    {   // spatial tail k = 256..287
        long long a[4];
#pragma unroll
        for (int mt = 0; mt < 4; ++mt)
            a[mt] = *reinterpret_cast<const long long*>(&w1t_f8[((wave * 4 + mt) * 64 + lane) * 8]);
#pragma unroll
        for (int nt = 0; nt < 4; ++nt) {
            long long b = *reinterpret_cast<const long long*>(&smH[(nt * 16 + l15) * S1 + 256 + quad * 8]);
#pragma unroll
            for (int mt = 0; mt < 4; ++mt)
                acc1[mt][nt] = __builtin_amdgcn_mfma_f32_16x16x32_fp8_fp8(a[mt], b, acc1[mt][nt], 0, 0, 0);
        }
    }

    // ---- epilogue1: + A_i[o] + B_j[o], relu, stats ----
    const int o0 = wave * 64;
    float vsum[4] = {}, vssq[4] = {};
#pragma unroll
    for (int mt = 0; mt < 4; ++mt) {
        int o = o0 + mt * 16 + quad * 4;
        float4 Ai = *reinterpret_cast<const float4*>(&AB[i * 512 + o]);
        float AiA[4] = {Ai.x, Ai.y, Ai.z, Ai.w};
#pragma unroll
        for (int nt = 0; nt < 4; ++nt) {
            int j = nt * 16 + l15;
            float4 Bj = *reinterpret_cast<const float4*>(&AB[(j0 + j) * 512 + 256 + o]);
            float BjA[4] = {Bj.x, Bj.y, Bj.z, Bj.w};
#pragma unroll
            for (int r = 0; r < 4; ++r) {
                float v = fmaxf(acc1[mt][nt][r] + AiA[r] + BjA[r], 0.f);
                acc1[mt][nt][r] = v;
                vsum[nt] += v; vssq[nt] += v * v;
            }
        }
    }
#pragma unroll
    for (int nt = 0; nt < 4; ++nt) {
        vsum[nt] += __shfl_xor(vsum[nt], 16, 64);
        vsum[nt] += __shfl_xor(vsum[nt], 32, 64);
        vssq[nt] += __shfl_xor(vssq[nt], 16, 64);
        vssq[nt] += __shfl_xor(vssq[nt], 32, 64);
    }
    if (quad == 0)
#pragma unroll
        for (int nt = 0; nt < 4; ++nt) {
            s_psum[nt * 16 + l15][wave] = vsum[nt];
            s_pssq[nt * 16 + l15][wave] = vssq[nt];
        }
    __syncthreads();                                          // B1: GEMM1 reads done
    // h1 fp8 write into smH (overwrites scaledA; WAR cleared by B1)
#pragma unroll
    for (int mt = 0; mt < 4; ++mt) {
        int o = o0 + mt * 16 + quad * 4;
#pragma unroll
        for (int nt = 0; nt < 4; ++nt) {
            int j = nt * 16 + l15;
            *reinterpret_cast<int*>(&smH[j * S1 + o]) =
                pk4_fp8(acc1[mt][nt][0], acc1[mt][nt][1], acc1[mt][nt][2], acc1[mt][nt][3]);
        }
    }
    if (wave == 0) {   // finalize LN stats
        int j = lane;
        float sm = (s_psum[j][0] + s_psum[j][1] + s_psum[j][2] + s_psum[j][3]) * (1.0f / 256.0f);
        float sq = (s_pssq[j][0] + s_pssq[j][1] + s_pssq[j][2] + s_pssq[j][3]) * (1.0f / 256.0f);
        s_mu[j] = sm;
        s_rs[j] = rsqrtf(sq - sm * sm + 1e-5f);
    }
    __syncthreads();                                          // B2: h1 + stats ready

    // ======== GEMM2 (MX, K=256): wave owns p-slice 32 ========
    f32x4 acc2[2][4] = {};
#pragma unroll
    for (int ks = 0; ks < 2; ++ks) {
        i32x8 a[2];
#pragma unroll
        for (int mt = 0; mt < 2; ++mt)
            a[mt] = *reinterpret_cast<const i32x8*>(&w2g_mx[((ks * 8 + wave * 2 + mt) * 64 + lane) * 32]);
#pragma unroll
        for (int nt = 0; nt < 4; ++nt) {
            i32x8 b = ld32_lds(&smH[(nt * 16 + l15) * S1 + ks * 128 + quad * 32]);
#pragma unroll
            for (int mt = 0; mt < 2; ++mt)
                acc2[mt][nt] = MFMA_MX(a[mt], b, acc2[mt][nt]);
        }
    }
    // epilogue2: LN-folded affine + relu -> h2 (separate region, no barrier)
#pragma unroll
    for (int mt = 0; mt < 2; ++mt) {
        int p = wave * 32 + mt * 16 + quad * 4;
        float4 C1 = *reinterpret_cast<const float4*>(&c1[p]);
        float4 C2 = *reinterpret_cast<const float4*>(&c2[p]);
        float C1A[4] = {C1.x, C1.y, C1.z, C1.w};
        float C2A[4] = {C2.x, C2.y, C2.z, C2.w};
#pragma unroll
        for (int nt = 0; nt < 4; ++nt) {
            int j = nt * 16 + l15;
            float mu = s_mu[j], rs = s_rs[j];
            float vv[4];
#pragma unroll
            for (int r = 0; r < 4; ++r)
                vv[r] = fmaxf(rs * (acc2[mt][nt][r] - mu * C2A[r]) + C1A[r], 0.f);
            *reinterpret_cast<int*>(&smH2[j * S2 + p]) = pk4_fp8(vv[0], vv[1], vv[2], vv[3]);
        }
    }
    __syncthreads();                                          // B3: h2 ready

    // ======== GEMM3 (MX, K=128): wave owns q-slice 16 ========
    f32x4 acc3[4] = {};
    {
        i32x8 a = *reinterpret_cast<const i32x8*>(&w3_mx[(wave * 64 + lane) * 32]);
#pragma unroll
        for (int nt = 0; nt < 4; ++nt) {
            i32x8 b = ld32_lds(&smH2[(nt * 16 + l15) * S2 + quad * 32]);
            acc3[nt] = MFMA_MX(a, b, acc3[nt]);
        }
    }
    {   // epilogue3 -> h3 (separate region, no pre-barrier)
        int q = wave * 16 + quad * 4;
        float4 B3 = *reinterpret_cast<const float4*>(&b3[q]);
        float B3A[4] = {B3.x, B3.y, B3.z, B3.w};
#pragma unroll
        for (int nt = 0; nt < 4; ++nt) {
            int j = nt * 16 + l15;
            float vv[4];
#pragma unroll
            for (int r = 0; r < 4; ++r)
                vv[r] = fmaxf(acc3[nt][r] + B3A[r], 0.f);
            *reinterpret_cast<int*>(&smH3[j * S3 + q]) = pk4_fp8(vv[0], vv[1], vv[2], vv[3]);
        }
    }
    __syncthreads();                                          // B4: h3 ready

    // ======== GEMM4 (16x16x32 fp8, K=64) + head ========
    const int mt4 = wave & 1;
    const int jh  = wave >> 1;
    f32x4 acc4[2] = {};
#pragma unroll
    for (int kc = 0; kc < 2; ++kc) {
        long long a = *reinterpret_cast<const long long*>(&w4_f8[((kc * 2 + mt4) * 64 + lane) * 8]);
#pragma unroll
        for (int nt = 0; nt < 2; ++nt) {
            int j = jh * 32 + nt * 16 + l15;
            long long b = *reinterpret_cast<const long long*>(&smH3[j * S3 + kc * 32 + quad * 8]);
            acc4[nt] = __builtin_amdgcn_mfma_f32_16x16x32_fp8_fp8(a, b, acc4[nt], 0, 0, 0);
        }
    }
    {
        int o4 = mt4 * 16 + quad * 4;
        float4 B4 = *reinterpret_cast<const float4*>(&b4[o4]);
        float4 W5 = *reinterpret_cast<const float4*>(&w5[o4]);
        float B4A[4] = {B4.x, B4.y, B4.z, B4.w};
        float W5A[4] = {W5.x, W5.y, W5.z, W5.w};
#pragma unroll
        for (int nt = 0; nt < 2; ++nt) {
            float part = 0.f;
#pragma unroll
            for (int r = 0; r < 4; ++r)
                part += fmaxf(acc4[nt][r] + B4A[r], 0.f) * W5A[r];
            part += __shfl_xor(part, 16, 64);
            part += __shfl_xor(part, 32, 64);
            if (quad == 0)
                s_l5[jh * 32 + nt * 16 + l15][mt4] = part;
        }
    }
    __syncthreads();                                          // B5
    if (tid < 64) {
        int j = j0 + tid;
        float v = s_l5[tid][0] + s_l5[tid][1] + b5[0];
        out[i * 768 + j] = (j == i) ? -1.0e9f : v;
    }
}

// ---------------------------------------------------------------------------
extern "C" void kernel_launch(void* const* d_in, const int* in_sizes, int n_in,
                              void* d_out, int out_size, void* d_ws, size_t ws_size,
                              hipStream_t stream)
{
    const float* features   = (const float*)d_in[0];
    const float* boxes      = (const float*)d_in[1];
    const float* in_proj_w  = (const float*)d_in[2];
    const float* in_proj_b  = (const float*)d_in[3];
    const float* out_proj_w = (const float*)d_in[4];
    const float* out_proj_b = (const float*)d_in[5];
    const float* w1  = (const float*)d_in[6];
    const float* b1  = (const float*)d_in[7];
    const float* ln_g = (const float*)d_in[8];
    const float* ln_b = (const float*)d_in[9];
    const float* w2  = (const float*)d_in[10];
    const float* b2  = (const float*)d_in[11];
    const float* w3  = (const float*)d_in[12];
    const float* b3  = (const float*)d_in[13];
    const float* w4  = (const float*)d_in[14];
    const float* b4  = (const float*)d_in[15];
    const float* w5  = (const float*)d_in[16];
    const float* b5  = (const float*)d_in[17];
    float* out = (float*)d_out;

    // ---- workspace layout ----
    char* p = (char*)d_ws;
    unsigned short* qkvb  = (unsigned short*)p; p += 768 * 768 * 2;
    unsigned short* Vt    = (unsigned short*)p; p += 256 * 768 * 2;
    unsigned short* Obf   = (unsigned short*)p; p += 768 * 256 * 2;
    unsigned short* WcatB = (unsigned short*)p; p += 196608 * 2;   // [outW;Wcomb]
    float* att = (float*)p; p += 768 * 256 * 4;
    float* AB  = (float*)p; p += 768 * 512 * 4;
    unsigned char* w1c_mx = (unsigned char*)p; p += 65536;
    unsigned char* w1t_f8 = (unsigned char*)p; p += 8192;
    unsigned char* w2g_mx = (unsigned char*)p; p += 32768;
    unsigned char* w3_mx  = (unsigned char*)p; p += 8192;
    unsigned char* w4_f8  = (unsigned char*)p; p += 2048;
    float* bias768 = (float*)p; p += 768 * 4;
    float* c1v     = (float*)p; p += 128 * 4;
    float* c2v     = (float*)p; p += 128 * 4;

    // 1) pack + Wcomb + qkv GEMM
    pack_all<<<dim3(1372), dim3(256), 0, stream>>>(features, in_proj_w,
        in_proj_b, out_proj_w, w1, w2, w3, w4, b1, ln_g, ln_b, b2, out_proj_b,
        qkvb, Vt, WcatB, w1c_mx, w1t_f8, w2g_mx, w3_mx, w4_f8,
        bias768, c1v, c2v);
    // 2) attention
    attn_mfma<<<dim3(8, 24), dim3(256), 0, stream>>>(qkvb, Vt, Obf);
    // 3) [att | AB] = O @ WcatB^T + bias768
    gemm_attab<<<dim3(12, 12), dim3(256), 0, stream>>>(Obf, WcatB, bias768,
        att, AB);
    // 4) pair MLP
    pair_mlp<<<dim3(768, 12), dim3(256), 0, stream>>>(att, AB,
        w1c_mx, w1t_f8, w2g_mx, w3_mx, w4_f8, boxes, c1v, c2v,
        b3, b4, w5, b5, out);
}